// Round 11
// baseline (173.525 us; speedup 1.0000x reference)
//
#include <hip/hip_runtime.h>
#include <math.h>

// GAT layer: N=50000 nodes, E=800000 edges, D_IN=D_OUT=128, H=4, D_H=32
//
// 6-dispatch pipeline:
//   k_setup  : pack W / out_w into bf16 MFMA B-fragments + zero gcnt/gcur
//   k_gemm1b : Wx = x @ W via MFMA -> COLUMN-BLOCKED bf16 layout
//              WxbB[b][node][8xu32] (8 slabs of 1.6 MB) + fused attention
//              scores s_i/s_j; trailing blocks do the dst-bucket histogram
//   k_bin1   : block-local counting sort -> bucket-contiguous tmp
//   k_bin2   : one block per bucket: node counts + scan (offs/cnts) +
//              placement + per-edge softmax numerators pexp[h][e] (head-major)
//   k_aggc   : column-split aggregation. Grid 8 x 3125; b = blockIdx%8 picks
//              the column slab -> with round-robin block->XCD dispatch each
//              1.6 MB slab is L2-resident on one XCD (the whole point).
//              8 lanes per edge (32B slab read), 4 nodes per wave, per-node
//              shfl reduce; writes f32 16-col slices directly into d_out.
//   k_gemm2  : in-place row transform out = elu(out @ out_w + out_b) (MFMA;
//              each wave reads its own 16 rows fully before writing them).

typedef __attribute__((ext_vector_type(8))) short short8;
typedef __attribute__((ext_vector_type(4))) float f32x4;

#define BIN_VPT 16          // edges per thread; 4096 edges per 256-thread block

__device__ __forceinline__ float lrelu(float v) { return v >= 0.f ? v : 0.2f * v; }

__device__ __forceinline__ unsigned short f2bf(float f) {  // RNE f32 -> bf16
  unsigned int u = __float_as_uint(f);
  u += 0x7FFFu + ((u >> 16) & 1u);
  return (unsigned short)(u >> 16);
}
// HW packed RNE convert: dst = bf16(lo) | bf16(hi)<<16
__device__ __forceinline__ unsigned int cvt_pk_bf16(float lo, float hi) {
  unsigned int r;
  asm("v_cvt_pk_bf16_f32 %0, %1, %2" : "=v"(r) : "v"(lo), "v"(hi));
  return r;
}
__device__ __forceinline__ float bflo(unsigned int w) { return __uint_as_float(w << 16); }
__device__ __forceinline__ float bfhi(unsigned int w) { return __uint_as_float(w & 0xFFFF0000u); }

// 256-thread exclusive scan helper (value v per thread -> returns excl; ws[4] LDS)
__device__ __forceinline__ int blk_excl_scan(int v, int* ws) {
  const int t = threadIdx.x, lane = t & 63, wv = t >> 6;
  int incl = v;
#pragma unroll
  for (int m = 1; m < 64; m <<= 1) {
    int x = __shfl_up(incl, m, 64);
    if (lane >= m) incl += x;
  }
  if (lane == 63) ws[wv] = incl;
  __syncthreads();
  int woff = 0;
  for (int p = 0; p < wv; ++p) woff += ws[p];
  return woff + incl - v;
}

// ---------------------------------------------------------------- setup
__global__ void k_setup(const float* __restrict__ W, const float* __restrict__ ow,
                        unsigned short* __restrict__ wf, unsigned short* __restrict__ owf,
                        int* __restrict__ gcnt, int* __restrict__ gcur) {
  const int t = blockIdx.x * 256 + threadIdx.x;
  if (blockIdx.x == 0) gcnt[threadIdx.x] = 0;
  if (blockIdx.x == 1) gcur[threadIdx.x] = 0;
  const int which = t >> 11;           // 0: W, 1: out_w
  const int tt = t & 2047;
  const float* M = which ? ow : W;
  unsigned short* F = which ? owf : wf;
  const int lane = tt & 63;
  const int nt = (tt >> 6) & 7;
  const int ks = tt >> 9;
  const int k0 = ks * 32 + (lane >> 4) * 8;
  const int col = nt * 16 + (lane & 15);
  short8 v;
#pragma unroll
  for (int j = 0; j < 8; ++j) v[j] = (short)f2bf(M[(k0 + j) * 128 + col]);
  *(short8*)(F + (size_t)tt * 8) = v;
}

// ---------------------------------------------------------------- GEMM1 + hist
__global__ void k_gemm1b(const float* __restrict__ x, const unsigned short* __restrict__ wf,
                         const float* __restrict__ attn, unsigned int* __restrict__ WxbB,
                         float* __restrict__ s_i, float* __restrict__ s_j, int n,
                         const int* __restrict__ dst, int* __restrict__ gcnt, int E,
                         int gemmBlocks) {
  __shared__ int lc[256];
  if (blockIdx.x >= gemmBlocks) {  // ---- histogram part
    const int bb = blockIdx.x - gemmBlocks;
    lc[threadIdx.x] = 0;
    __syncthreads();
    const int base = bb * (256 * BIN_VPT);
#pragma unroll
    for (int j = 0; j < BIN_VPT; ++j) {
      int e = base + j * 256 + threadIdx.x;
      if (e < E) atomicAdd(&lc[((unsigned int)dst[e]) >> 8], 1);
    }
    __syncthreads();
    int c = lc[threadIdx.x];
    if (c) atomicAdd(&gcnt[threadIdx.x], c);
    return;
  }

  // ---- GEMM part: one wave = 16-row strip, acc[nt] covers cols nt*16..+15
  const int lane = threadIdx.x & 63;
  const int gw = blockIdx.x * (blockDim.x >> 6) + (threadIdx.x >> 6);
  const int r0 = gw * 16;
  if (r0 >= n) return;
  const int g = lane >> 4, c = lane & 15;

  f32x4 acc[8];
#pragma unroll
  for (int nt = 0; nt < 8; ++nt) acc[nt] = (f32x4){0.f, 0.f, 0.f, 0.f};

  const int arow = min(r0 + c, n - 1);
#pragma unroll
  for (int ks = 0; ks < 4; ++ks) {
    const float* xr = x + (size_t)arow * 128 + ks * 32 + g * 8;
    float4 v0 = *(const float4*)xr;
    float4 v1 = *(const float4*)(xr + 4);
    uint4 au;
    au.x = cvt_pk_bf16(v0.x, v0.y);
    au.y = cvt_pk_bf16(v0.z, v0.w);
    au.z = cvt_pk_bf16(v1.x, v1.y);
    au.w = cvt_pk_bf16(v1.z, v1.w);
    short8 af = __builtin_bit_cast(short8, au);
#pragma unroll
    for (int nt = 0; nt < 8; ++nt) {
      short8 bf = *(const short8*)(wf + ((size_t)(ks * 8 + nt) * 64 + lane) * 8);
      acc[nt] = __builtin_amdgcn_mfma_f32_16x16x32_bf16(af, bf, acc[nt], 0, 0, 0);
    }
  }

  const int odd = c & 1;
#pragma unroll
  for (int r = 0; r < 4; ++r) {
    const int row = r0 + g * 4 + r;
    if (row >= n) continue;
#pragma unroll
    for (int ntp = 0; ntp < 4; ++ntp) {
      float ve = acc[ntp][r], vo = acc[ntp + 4][r];
      float vex = __shfl_xor(ve, 1, 64);
      float vox = __shfl_xor(vo, 1, 64);
      const int nt = odd ? ntp + 4 : ntp;
      // column-blocked: slab nt, node row, u32 col chunk c>>1
      WxbB[((size_t)nt * n + row) * 8 + (c >> 1)] =
          cvt_pk_bf16(odd ? vox : ve, odd ? vo : vex);
    }
  }

  float aiv[8], ajv[8];
#pragma unroll
  for (int nt = 0; nt < 8; ++nt) {
    const int hh = nt >> 1, ch = (nt & 1) * 16 + c;
    aiv[nt] = attn[hh * 64 + ch];
    ajv[nt] = attn[hh * 64 + 32 + ch];
  }
#pragma unroll
  for (int r = 0; r < 4; ++r) {
    float pih[4], pjh[4];
#pragma unroll
    for (int h = 0; h < 4; ++h) {
      pih[h] = acc[2 * h][r] * aiv[2 * h] + acc[2 * h + 1][r] * aiv[2 * h + 1];
      pjh[h] = acc[2 * h][r] * ajv[2 * h] + acc[2 * h + 1][r] * ajv[2 * h + 1];
    }
#pragma unroll
    for (int m = 1; m < 16; m <<= 1) {
#pragma unroll
      for (int h = 0; h < 4; ++h) {
        pih[h] += __shfl_xor(pih[h], m, 64);
        pjh[h] += __shfl_xor(pjh[h], m, 64);
      }
    }
    const int row = r0 + g * 4 + r;
    if (c == 0 && row < n) {
#pragma unroll
      for (int h = 0; h < 4; ++h) {
        s_i[(size_t)row * 4 + h] = pih[h];
        s_j[(size_t)row * 4 + h] = pjh[h];
      }
    }
  }
}

// ---------------------------------------------------------------- bin1
__global__ void k_bin1(const int* __restrict__ edges, const int* __restrict__ gcnt,
                       int* __restrict__ gcur, unsigned int* __restrict__ tmp, int E) {
  __shared__ int ws[4];
  __shared__ int bst_s[256];
  __shared__ int lcnt[256];
  __shared__ int lbase[256];
  const int t = threadIdx.x;
  const int excl = blk_excl_scan(gcnt[t], ws);
  bst_s[t] = excl;
  lcnt[t] = 0;
  __syncthreads();
  const int base = blockIdx.x * (256 * BIN_VPT);
  unsigned int pv[BIN_VPT];
  int rk[BIN_VPT];
#pragma unroll
  for (int j = 0; j < BIN_VPT; ++j) {
    int e = base + j * 256 + t;
    if (e < E) {
      unsigned int s = (unsigned int)edges[e];
      unsigned int d = (unsigned int)edges[E + e];
      pv[j] = s | (d << 16);
      rk[j] = atomicAdd(&lcnt[d >> 8], 1);
    } else {
      pv[j] = 0u;
      rk[j] = -1;
    }
  }
  __syncthreads();
  const int c = lcnt[t];
  lbase[t] = bst_s[t] + (c ? atomicAdd(&gcur[t], c) : 0);
  __syncthreads();
#pragma unroll
  for (int j = 0; j < BIN_VPT; ++j) {
    if (rk[j] >= 0) {
      const int b = pv[j] >> 24;  // dst >> 8
      tmp[lbase[b] + rk[j]] = pv[j];
    }
  }
}

// ---------------------------------------------------------------- bin2
// one block per bucket: node counts -> scan (offs/cnts) -> placement.
// Placement also computes per-edge softmax numerators into head-major planes
// pexp[h*E + pos] so each aggc XCD streams one coalesced plane.
__global__ void k_bin2(const unsigned int* __restrict__ tmp, const int* __restrict__ gcnt,
                       const float* __restrict__ s_i, const float* __restrict__ s_j,
                       int* __restrict__ csr, float* __restrict__ pexp,
                       int* __restrict__ offs, int* __restrict__ cnts, int n, int E) {
  __shared__ int ws[4];
  __shared__ int bst_s[256];
  __shared__ int nc[256];
  __shared__ float sjs[256][4];
  const int b = blockIdx.x;
  const int t = threadIdx.x;
  bst_s[t] = blk_excl_scan(gcnt[t], ws);
  nc[t] = 0;
  {
    const int node = b * 256 + t;
    float4 sj = make_float4(0.f, 0.f, 0.f, 0.f);
    if (node < n) sj = *(const float4*)(s_j + (size_t)node * 4);
    *(float4*)&sjs[t][0] = sj;
  }
  __syncthreads();
  const int base = bst_s[b], cnt = gcnt[b];
  for (int i = t; i < cnt; i += 256)
    atomicAdd(&nc[(tmp[base + i] >> 16) & 255], 1);
  __syncthreads();
  const int node = b * 256 + t;
  const int c = nc[t];
  if (node < n) cnts[node] = c;
  __syncthreads();           // blk_excl_scan reuses ws; ensure count phase done
  const int excl = blk_excl_scan(c, ws);
  if (node < n) offs[node] = base + excl;
  __syncthreads();           // everyone done reading nc from count phase
  nc[t] = excl;              // becomes local cursor
  __syncthreads();
  for (int i = t; i < cnt; i += 256) {
    unsigned int v = tmp[base + i];
    const int srcv = (int)(v & 0xFFFFu);
    const int loc = (v >> 16) & 255;
    int pos = base + atomicAdd(&nc[loc], 1);
    const float4 si = *(const float4*)(s_i + (size_t)srcv * 4);
    const float4 sj = *(const float4*)&sjs[loc][0];
    csr[pos] = srcv;
    pexp[0 * (size_t)E + pos] = __expf(lrelu(si.x + sj.x));
    pexp[1 * (size_t)E + pos] = __expf(lrelu(si.y + sj.y));
    pexp[2 * (size_t)E + pos] = __expf(lrelu(si.z + sj.z));
    pexp[3 * (size_t)E + pos] = __expf(lrelu(si.w + sj.w));
  }
}

// ---------------------------------------------------------------- aggc
// Column-split aggregation. b = blockIdx%8 -> 16-col slab (1.6 MB, L2-local
// per XCD under round-robin dispatch). 4 waves/block, 4 nodes/wave, 8 lanes
// per edge (eg = lane>>3), lane cl = lane&7 owns u32 col chunk (2 bf16 cols).
#define AGGC_FULL(kk)                                                     \
  {                                                                       \
    const int pos_ = base + (kk) + eg;                                    \
    const int src_ = csr[pos_];                                           \
    const float p_ = pe[pos_];                                            \
    const unsigned int w_ = slab[((size_t)src_ << 3) | (unsigned)cl];     \
    a0 += p_ * bflo(w_); a1 += p_ * bfhi(w_); smh += p_;                  \
  }
#define AGGC_TAIL(kk)                                                     \
  {                                                                       \
    const int c1_ = deg - (kk);                                           \
    const int pos_ = base + (kk) + min(eg, c1_ - 1);                      \
    const int src_ = csr[pos_];                                           \
    const float p_ = (eg < c1_) ? pe[pos_] : 0.f;                         \
    const unsigned int w_ = slab[((size_t)src_ << 3) | (unsigned)cl];     \
    a0 += p_ * bflo(w_); a1 += p_ * bfhi(w_); smh += p_;                  \
  }

__global__ void k_aggc(const unsigned int* __restrict__ WxbB,
                       const int* __restrict__ offs, const int* __restrict__ cnts,
                       const int* __restrict__ csr, const float* __restrict__ pexp,
                       float* __restrict__ out, int n, int E) {
  const int b = blockIdx.x & 7;          // col block (cols b*16 .. b*16+15)
  const int ng = blockIdx.x >> 3;        // node group of 16
  const int lane = threadIdx.x & 63;
  const int wv = threadIdx.x >> 6;
  const int eg = lane >> 3;              // edge subgroup 0..7
  const int cl = lane & 7;               // u32 col chunk within block
  const unsigned int* slab = WxbB + (size_t)b * n * 8;
  const float* pe = pexp + (size_t)(b >> 1) * E;   // head = b>>1
  const int nd0w = ng * 16 + wv * 4;

#pragma unroll
  for (int cur = 0; cur < 4; ++cur) {
    const int node = nd0w + cur;
    if (node >= n) break;
    const int base = offs[node];
    const int deg = cnts[node];
    float a0 = 0.f, a1 = 0.f, smh = 0.f;
    int k = 0;
    for (; k + 16 <= deg; k += 16) { AGGC_FULL(k) AGGC_FULL(k + 8) }
    if (k + 8 <= deg) { AGGC_FULL(k) k += 8; }
    if (k < deg) AGGC_TAIL(k)
#pragma unroll
    for (int mm = 8; mm < 64; mm <<= 1) {
      a0 += __shfl_xor(a0, mm, 64);
      a1 += __shfl_xor(a1, mm, 64);
      smh += __shfl_xor(smh, mm, 64);
    }
    const float inv = 1.f / (smh + 1e-16f);
    if (eg == 0)
      *(float2*)(out + (size_t)node * 128 + b * 16 + cl * 2) =
          make_float2(a0 * inv, a1 * inv);
  }
}

// ---------------------------------------------------------------- GEMM 2
// In-place: out = elu(out @ out_w + out_b). Each wave reads only its own 16
// rows (fully, before any write), so in-place is race-free.
__global__ void k_gemm2(float* __restrict__ io, const unsigned short* __restrict__ owf,
                        const float* __restrict__ ob, int n) {
  const int lane = threadIdx.x & 63;
  const int gw = blockIdx.x * (blockDim.x >> 6) + (threadIdx.x >> 6);
  const int r0 = gw * 16;
  if (r0 >= n) return;
  const int g = lane >> 4, c = lane & 15;

  f32x4 acc[8];
#pragma unroll
  for (int nt = 0; nt < 8; ++nt) acc[nt] = (f32x4){0.f, 0.f, 0.f, 0.f};

  const int arow = min(r0 + c, n - 1);
#pragma unroll
  for (int ks = 0; ks < 4; ++ks) {
    const float* xr = io + (size_t)arow * 128 + ks * 32 + g * 8;
    float4 v0 = *(const float4*)xr;
    float4 v1 = *(const float4*)(xr + 4);
    uint4 au;
    au.x = cvt_pk_bf16(v0.x, v0.y);
    au.y = cvt_pk_bf16(v0.z, v0.w);
    au.z = cvt_pk_bf16(v1.x, v1.y);
    au.w = cvt_pk_bf16(v1.z, v1.w);
    short8 af = __builtin_bit_cast(short8, au);
#pragma unroll
    for (int nt = 0; nt < 8; ++nt) {
      short8 bf = *(const short8*)(owf + ((size_t)(ks * 8 + nt) * 64 + lane) * 8);
      acc[nt] = __builtin_amdgcn_mfma_f32_16x16x32_bf16(af, bf, acc[nt], 0, 0, 0);
    }
  }

#pragma unroll
  for (int r = 0; r < 4; ++r) {
    const int row = r0 + g * 4 + r;
    if (row >= n) continue;
    float* dst = io + (size_t)row * 128;
#pragma unroll
    for (int nt = 0; nt < 8; ++nt) {
      float v = acc[nt][r] + ob[nt * 16 + c];
      v = v > 0.f ? v : expm1f(v);
      dst[nt * 16 + c] = v;
    }
  }
}

// ---------------------------------------------------------------- launch
extern "C" void kernel_launch(void* const* d_in, const int* in_sizes, int n_in,
                              void* d_out, int out_size, void* d_ws, size_t ws_size,
                              hipStream_t stream) {
  const float* x    = (const float*)d_in[0];
  const int*   edges = (const int*)d_in[1];   // [2,E] (src row then dst row)
  const float* W    = (const float*)d_in[2];
  const float* attn = (const float*)d_in[3];
  const float* ow   = (const float*)d_in[4];
  const float* ob   = (const float*)d_in[5];
  const int n = in_sizes[0] / 128;            // 50000 (< 65536: u32 edge pack)
  const int E = in_sizes[1] / 2;
  float* out = (float*)d_out;

  char* wp = (char*)d_ws;
  auto alloc = [&](size_t bytes) {
    char* p = wp;
    wp += (bytes + 255) & ~(size_t)255;
    return p;
  };
  unsigned short* wf  = (unsigned short*)alloc(2048 * 8 * 2);
  unsigned short* owf = (unsigned short*)alloc(2048 * 8 * 2);
  unsigned int*   WxbB = (unsigned int*)alloc((size_t)n * 64 * 4);  // 8 slabs
  float* s_i    = (float*)alloc((size_t)n * 4 * 4);
  float* s_j    = (float*)alloc((size_t)n * 4 * 4);
  int*   gcnt   = (int*)alloc(256 * 4);
  int*   gcur   = (int*)alloc(256 * 4);
  int*   offs   = (int*)alloc((size_t)n * 4);
  int*   cnts   = (int*)alloc((size_t)n * 4);
  unsigned int* tmp = (unsigned int*)alloc((size_t)E * 4);
  int*   csr    = (int*)alloc((size_t)E * 4);
  float* pexp   = (float*)alloc((size_t)E * 4 * 4);   // head-major [4][E]

  dim3 blk(256);
  const int NB = (n + 255) / 256;                            // node buckets (196)
  const int EB = (E + 256 * BIN_VPT - 1) / (256 * BIN_VPT);  // edge blocks (196)
  const int strips = (n + 15) / 16;
  const int gemmBlocks = (strips + 3) / 4;
  const int aggBlocks = 8 * ((n + 15) / 16);                 // 8 col-blocks

  k_setup<<<16, blk, 0, stream>>>(W, ow, wf, owf, gcnt, gcur);
  k_gemm1b<<<gemmBlocks + EB, blk, 0, stream>>>(x, wf, attn, WxbB, s_i, s_j, n,
                                                edges + E, gcnt, E, gemmBlocks);
  k_bin1<<<EB, blk, 0, stream>>>(edges, gcnt, gcur, tmp, E);
  k_bin2<<<NB, blk, 0, stream>>>(tmp, gcnt, s_i, s_j, csr, pexp, offs, cnts, n, E);
  k_aggc<<<aggBlocks, blk, 0, stream>>>(WxbB, offs, cnts, csr, pexp, out, n, E);
  k_gemm2<<<gemmBlocks, blk, 0, stream>>>(out, owf, ob, n);
}

// Round 12
// 108.634 us; speedup vs baseline: 1.5973x; 1.5973x over previous
//
#include <hip/hip_runtime.h>
#include <math.h>

// GAT layer: N=50000 nodes, E=800000 edges, D_IN=D_OUT=128, H=4, D_H=32
//
// 5-dispatch pipeline (r7 structure + double-buffered staging in k_aggm):
//   k_setup  : pack W / out_w into bf16 MFMA B-fragments + zero gcnt/gcur
//   k_gemm1b : Wx(bf16) = x @ W via MFMA + fused attention scores s_i/s_j;
//              trailing blocks do the dst-bucket histogram (bucket = dst>>8)
//   k_bin1   : block-local counting sort -> bucket-contiguous tmp
//   k_bin2   : one block per bucket: node counts + scan (emits offs/cnts) +
//              placement — all scatter block-private
//   k_aggm   : 4 waves/block, 4 consecutive nodes per wave. Staging is
//              DOUBLE-BUFFERED: chunk c+1's csr/s_j/s_i loads issue into
//              registers before chunk c is consumed (T14 issue-early /
//              write-late), hiding the ~1200-cycle dependent gather chain
//              under the consumer loop. Consumer: full 256B row per wave
//              instruction, 8 rows in flight. Phase 2: output GEMM (MFMA)
//              + bias + ELU from the LDS tile.

typedef __attribute__((ext_vector_type(8))) short short8;
typedef __attribute__((ext_vector_type(4))) float f32x4;

#define BIN_VPT 16          // edges per thread; 4096 edges per 256-thread block

__device__ __forceinline__ float lrelu(float v) { return v >= 0.f ? v : 0.2f * v; }

__device__ __forceinline__ unsigned short f2bf(float f) {  // RNE f32 -> bf16
  unsigned int u = __float_as_uint(f);
  u += 0x7FFFu + ((u >> 16) & 1u);
  return (unsigned short)(u >> 16);
}
// HW packed RNE convert: dst = bf16(lo) | bf16(hi)<<16
__device__ __forceinline__ unsigned int cvt_pk_bf16(float lo, float hi) {
  unsigned int r;
  asm("v_cvt_pk_bf16_f32 %0, %1, %2" : "=v"(r) : "v"(lo), "v"(hi));
  return r;
}
__device__ __forceinline__ float bflo(unsigned int w) { return __uint_as_float(w << 16); }
__device__ __forceinline__ float bfhi(unsigned int w) { return __uint_as_float(w & 0xFFFF0000u); }

// 256-thread exclusive scan helper (value v per thread -> returns excl; ws[4] LDS)
__device__ __forceinline__ int blk_excl_scan(int v, int* ws) {
  const int t = threadIdx.x, lane = t & 63, wv = t >> 6;
  int incl = v;
#pragma unroll
  for (int m = 1; m < 64; m <<= 1) {
    int x = __shfl_up(incl, m, 64);
    if (lane >= m) incl += x;
  }
  if (lane == 63) ws[wv] = incl;
  __syncthreads();
  int woff = 0;
  for (int p = 0; p < wv; ++p) woff += ws[p];
  return woff + incl - v;
}

// ---------------------------------------------------------------- setup
__global__ void k_setup(const float* __restrict__ W, const float* __restrict__ ow,
                        unsigned short* __restrict__ wf, unsigned short* __restrict__ owf,
                        int* __restrict__ gcnt, int* __restrict__ gcur) {
  const int t = blockIdx.x * 256 + threadIdx.x;
  if (blockIdx.x == 0) gcnt[threadIdx.x] = 0;
  if (blockIdx.x == 1) gcur[threadIdx.x] = 0;
  const int which = t >> 11;           // 0: W, 1: out_w
  const int tt = t & 2047;
  const float* M = which ? ow : W;
  unsigned short* F = which ? owf : wf;
  const int lane = tt & 63;
  const int nt = (tt >> 6) & 7;
  const int ks = tt >> 9;
  const int k0 = ks * 32 + (lane >> 4) * 8;
  const int col = nt * 16 + (lane & 15);
  short8 v;
#pragma unroll
  for (int j = 0; j < 8; ++j) v[j] = (short)f2bf(M[(k0 + j) * 128 + col]);
  *(short8*)(F + (size_t)tt * 8) = v;
}

// ---------------------------------------------------------------- GEMM1 + hist
__global__ void k_gemm1b(const float* __restrict__ x, const unsigned short* __restrict__ wf,
                         const float* __restrict__ attn, unsigned int* __restrict__ Wxb,
                         float* __restrict__ s_i, float* __restrict__ s_j, int n,
                         const int* __restrict__ dst, int* __restrict__ gcnt, int E,
                         int gemmBlocks) {
  __shared__ int lc[256];
  if (blockIdx.x >= gemmBlocks) {  // ---- histogram part
    const int bb = blockIdx.x - gemmBlocks;
    lc[threadIdx.x] = 0;
    __syncthreads();
    const int base = bb * (256 * BIN_VPT);
#pragma unroll
    for (int j = 0; j < BIN_VPT; ++j) {
      int e = base + j * 256 + threadIdx.x;
      if (e < E) atomicAdd(&lc[((unsigned int)dst[e]) >> 8], 1);
    }
    __syncthreads();
    int c = lc[threadIdx.x];
    if (c) atomicAdd(&gcnt[threadIdx.x], c);
    return;
  }

  // ---- GEMM part: one wave = 16-row strip, acc[nt] covers cols nt*16..+15
  const int lane = threadIdx.x & 63;
  const int gw = blockIdx.x * (blockDim.x >> 6) + (threadIdx.x >> 6);
  const int r0 = gw * 16;
  if (r0 >= n) return;
  const int g = lane >> 4, c = lane & 15;

  f32x4 acc[8];
#pragma unroll
  for (int nt = 0; nt < 8; ++nt) acc[nt] = (f32x4){0.f, 0.f, 0.f, 0.f};

  const int arow = min(r0 + c, n - 1);
#pragma unroll
  for (int ks = 0; ks < 4; ++ks) {
    const float* xr = x + (size_t)arow * 128 + ks * 32 + g * 8;
    float4 v0 = *(const float4*)xr;
    float4 v1 = *(const float4*)(xr + 4);
    uint4 au;
    au.x = cvt_pk_bf16(v0.x, v0.y);
    au.y = cvt_pk_bf16(v0.z, v0.w);
    au.z = cvt_pk_bf16(v1.x, v1.y);
    au.w = cvt_pk_bf16(v1.z, v1.w);
    short8 af = __builtin_bit_cast(short8, au);
#pragma unroll
    for (int nt = 0; nt < 8; ++nt) {
      short8 bf = *(const short8*)(wf + ((size_t)(ks * 8 + nt) * 64 + lane) * 8);
      acc[nt] = __builtin_amdgcn_mfma_f32_16x16x32_bf16(af, bf, acc[nt], 0, 0, 0);
    }
  }

  const int odd = c & 1;
#pragma unroll
  for (int r = 0; r < 4; ++r) {
    const int row = r0 + g * 4 + r;
    if (row >= n) continue;
    unsigned int* dp = Wxb + (size_t)row * 64;
#pragma unroll
    for (int ntp = 0; ntp < 4; ++ntp) {
      float ve = acc[ntp][r], vo = acc[ntp + 4][r];
      float vex = __shfl_xor(ve, 1, 64);
      float vox = __shfl_xor(vo, 1, 64);
      const int nt = odd ? ntp + 4 : ntp;
      dp[nt * 8 + (c >> 1)] = cvt_pk_bf16(odd ? vox : ve, odd ? vo : vex);
    }
  }

  float aiv[8], ajv[8];
#pragma unroll
  for (int nt = 0; nt < 8; ++nt) {
    const int hh = nt >> 1, ch = (nt & 1) * 16 + c;
    aiv[nt] = attn[hh * 64 + ch];
    ajv[nt] = attn[hh * 64 + 32 + ch];
  }
#pragma unroll
  for (int r = 0; r < 4; ++r) {
    float pih[4], pjh[4];
#pragma unroll
    for (int h = 0; h < 4; ++h) {
      pih[h] = acc[2 * h][r] * aiv[2 * h] + acc[2 * h + 1][r] * aiv[2 * h + 1];
      pjh[h] = acc[2 * h][r] * ajv[2 * h] + acc[2 * h + 1][r] * ajv[2 * h + 1];
    }
#pragma unroll
    for (int m = 1; m < 16; m <<= 1) {
#pragma unroll
      for (int h = 0; h < 4; ++h) {
        pih[h] += __shfl_xor(pih[h], m, 64);
        pjh[h] += __shfl_xor(pjh[h], m, 64);
      }
    }
    const int row = r0 + g * 4 + r;
    if (c == 0 && row < n) {
#pragma unroll
      for (int h = 0; h < 4; ++h) {
        s_i[(size_t)row * 4 + h] = pih[h];
        s_j[(size_t)row * 4 + h] = pjh[h];
      }
    }
  }
}

// ---------------------------------------------------------------- bin1
__global__ void k_bin1(const int* __restrict__ edges, const int* __restrict__ gcnt,
                       int* __restrict__ gcur, unsigned int* __restrict__ tmp, int E) {
  __shared__ int ws[4];
  __shared__ int bst_s[256];
  __shared__ int lcnt[256];
  __shared__ int lbase[256];
  const int t = threadIdx.x;
  const int excl = blk_excl_scan(gcnt[t], ws);
  bst_s[t] = excl;
  lcnt[t] = 0;
  __syncthreads();
  const int base = blockIdx.x * (256 * BIN_VPT);
  unsigned int pv[BIN_VPT];
  int rk[BIN_VPT];
#pragma unroll
  for (int j = 0; j < BIN_VPT; ++j) {
    int e = base + j * 256 + t;
    if (e < E) {
      unsigned int s = (unsigned int)edges[e];
      unsigned int d = (unsigned int)edges[E + e];
      pv[j] = s | (d << 16);
      rk[j] = atomicAdd(&lcnt[d >> 8], 1);
    } else {
      pv[j] = 0u;
      rk[j] = -1;
    }
  }
  __syncthreads();
  const int c = lcnt[t];
  lbase[t] = bst_s[t] + (c ? atomicAdd(&gcur[t], c) : 0);
  __syncthreads();
#pragma unroll
  for (int j = 0; j < BIN_VPT; ++j) {
    if (rk[j] >= 0) {
      const int b = pv[j] >> 24;  // dst >> 8
      tmp[lbase[b] + rk[j]] = pv[j];
    }
  }
}

// ---------------------------------------------------------------- bin2
__global__ void k_bin2(const unsigned int* __restrict__ tmp, const int* __restrict__ gcnt,
                       int* __restrict__ csr, int* __restrict__ offs,
                       int* __restrict__ cnts, int n) {
  __shared__ int ws[4];
  __shared__ int bst_s[256];
  __shared__ int nc[256];
  const int b = blockIdx.x;
  const int t = threadIdx.x;
  bst_s[t] = blk_excl_scan(gcnt[t], ws);
  nc[t] = 0;
  __syncthreads();
  const int base = bst_s[b], cnt = gcnt[b];
  for (int i = t; i < cnt; i += 256)
    atomicAdd(&nc[(tmp[base + i] >> 16) & 255], 1);
  __syncthreads();
  const int node = b * 256 + t;
  const int c = nc[t];
  if (node < n) cnts[node] = c;
  __syncthreads();           // blk_excl_scan reuses ws; ensure count phase done
  const int excl = blk_excl_scan(c, ws);
  if (node < n) offs[node] = base + excl;
  __syncthreads();           // everyone done reading nc from count phase
  nc[t] = excl;              // becomes local cursor
  __syncthreads();
  for (int i = t; i < cnt; i += 256) {
    unsigned int v = tmp[base + i];
    int pos = atomicAdd(&nc[(v >> 16) & 255], 1);
    csr[base + pos] = (int)(v & 0xFFFFu);
  }
}

// ---------------------------------------------------------------- agg + GEMM2
// 4 waves/block (256 thr), 16 nodes/block, 4 consecutive nodes per wave.
// Double-buffered staging; consumer = full 256B row per wave instruction.
#define AGG_EDGE(e)                                                     \
  {                                                                     \
    int s_ = lsrc[wv][buf][e];                                          \
    float p_ = lp[wv][buf][e][h];                                       \
    unsigned int w_ = Wxb[(unsigned)(s_ << 6) | (unsigned)lane];        \
    acc.x += p_ * bflo(w_);                                             \
    acc.y += p_ * bfhi(w_);                                             \
    smh += p_;                                                          \
  }

__global__ void __launch_bounds__(256, 8)
k_aggm(const unsigned int* __restrict__ Wxb, const float* __restrict__ s_i,
       const float* __restrict__ s_j, const int* __restrict__ offs,
       const int* __restrict__ cnts, const int* __restrict__ csr_src,
       const unsigned short* __restrict__ owf, const float* __restrict__ ob,
       float* __restrict__ out, int n) {
  __shared__ unsigned int aTile[16][65];
  __shared__ int   lsrc[4][2][64];
  __shared__ float lp[4][2][64][4];
  const int lane = threadIdx.x & 63;
  const int wv = threadIdx.x >> 6;
  const int nd0 = blockIdx.x * 16;
  const int nd0w = nd0 + wv * 4;       // first of this wave's 4 nodes
  const int h = lane >> 4;

  // per-node degrees in lanes 0..3; boundaries within the wave span
  int degv = 0;
  if (lane < 4 && nd0w + lane < n) degv = cnts[nd0w + lane];
  const int wbase = (nd0w < n) ? offs[nd0w] : 0;
  const int d0 = __shfl(degv, 0, 64), d1 = __shfl(degv, 1, 64);
  const int d2 = __shfl(degv, 2, 64), d3 = __shfl(degv, 3, 64);
  const int b0 = d0, b1 = d0 + d1, b2 = b1 + d2;
  const int tot = b2 + d3;

  int cur = 0;
  int rem = d0;
  float2 acc = make_float2(0.f, 0.f);
  float smh = 0.f;

  // leading zero-degree nodes
  while (cur < 4 && rem == 0) {
    if (nd0w + cur < n) aTile[(wv << 2) + cur][lane] = 0u;  // agg row = 0
    ++cur;
    rem = (cur == 1) ? d1 : (cur == 2) ? d2 : (cur == 3) ? d3 : 0;
  }

  // ---- prefetch chunk 0 into registers (issue-early)
  int    src_r = 0;
  float4 si_r = make_float4(0.f, 0.f, 0.f, 0.f);
  float4 sj_r = make_float4(0.f, 0.f, 0.f, 0.f);
  if (tot > 0 && lane < min(64, tot)) {
    const int pos = lane;
    src_r = csr_src[wbase + pos];
    const int nl = (pos >= b0) + (pos >= b1) + (pos >= b2);
    sj_r = *(const float4*)(s_j + (size_t)(nd0w + nl) * 4);
    si_r = *(const float4*)(s_i + (size_t)src_r * 4);
  }

  int buf = 0;
  for (int c0 = 0; c0 < tot; c0 += 64) {
    const int m = min(64, tot - c0);
    // ---- write-late: convert staged regs -> LDS (buffer `buf`)
    if (lane < m) {
      float4 p;
      p.x = __expf(lrelu(si_r.x + sj_r.x));
      p.y = __expf(lrelu(si_r.y + sj_r.y));
      p.z = __expf(lrelu(si_r.z + sj_r.z));
      p.w = __expf(lrelu(si_r.w + sj_r.w));
      lsrc[wv][buf][lane] = src_r;
      *(float4*)&lp[wv][buf][lane][0] = p;
    }
    // ---- issue-early: prefetch chunk c0+64 into registers
    const int c1 = c0 + 64;
    if (c1 < tot) {
      const int m2 = min(64, tot - c1);
      if (lane < m2) {
        const int pos = c1 + lane;
        src_r = csr_src[wbase + pos];
        const int nl = (pos >= b0) + (pos >= b1) + (pos >= b2);
        sj_r = *(const float4*)(s_j + (size_t)(nd0w + nl) * 4);
        si_r = *(const float4*)(s_i + (size_t)src_r * 4);
      }
    }
    asm volatile("s_waitcnt lgkmcnt(0)" ::: "memory");  // same-wave LDS RAW
    // ---- consume chunk `buf`
    int k = 0;
    while (k < m) {
      const int take = min(m - k, rem);
      int e = k;
      const int end = k + take;
      for (; e + 8 <= end; e += 8) {  // 8 independent 256B row loads in flight
        AGG_EDGE(e + 0) AGG_EDGE(e + 1) AGG_EDGE(e + 2) AGG_EDGE(e + 3)
        AGG_EDGE(e + 4) AGG_EDGE(e + 5) AGG_EDGE(e + 6) AGG_EDGE(e + 7)
      }
      for (; e + 4 <= end; e += 4) {
        AGG_EDGE(e + 0) AGG_EDGE(e + 1) AGG_EDGE(e + 2) AGG_EDGE(e + 3)
      }
      for (; e < end; ++e) AGG_EDGE(e)
      k += take;
      rem -= take;
      while (rem == 0 && cur < 4) {  // finalize node(s); skip zero-deg
        const float inv = 1.f / (smh + 1e-16f);
        if (nd0w + cur < n)
          aTile[(wv << 2) + cur][lane] = cvt_pk_bf16(acc.x * inv, acc.y * inv);
        ++cur;
        acc.x = 0.f; acc.y = 0.f; smh = 0.f;
        rem = (cur == 1) ? d1 : (cur == 2) ? d2 : (cur == 3) ? d3 : 0;
      }
      if (cur >= 4) break;
    }
    buf ^= 1;
  }
  __syncthreads();

  // ---- phase 2: out-GEMM on the 16-row tile; each wave does 2 col-tiles
  const int g = lane >> 4, c = lane & 15;
#pragma unroll
  for (int t2 = 0; t2 < 2; ++t2) {
    const int nt = wv + t2 * 4;
    f32x4 o = (f32x4){0.f, 0.f, 0.f, 0.f};
#pragma unroll
    for (int ks = 0; ks < 4; ++ks) {
      uint4 au = *(const uint4*)&aTile[c][ks * 16 + g * 4];  // A row = lane&15
      short8 af = __builtin_bit_cast(short8, au);
      short8 bf = *(const short8*)(owf + ((size_t)(ks * 8 + nt) * 64 + lane) * 8);
      o = __builtin_amdgcn_mfma_f32_16x16x32_bf16(af, bf, o, 0, 0, 0);
    }
#pragma unroll
    for (int r = 0; r < 4; ++r) {
      const int row = nd0 + g * 4 + r;   // D row = (lane>>4)*4 + r
      if (row < n) {
        float v = o[r] + ob[nt * 16 + c];
        v = v > 0.f ? v : expm1f(v);
        out[(size_t)row * 128 + nt * 16 + c] = v;
      }
    }
  }
}

// ---------------------------------------------------------------- launch
extern "C" void kernel_launch(void* const* d_in, const int* in_sizes, int n_in,
                              void* d_out, int out_size, void* d_ws, size_t ws_size,
                              hipStream_t stream) {
  const float* x    = (const float*)d_in[0];
  const int*   edges = (const int*)d_in[1];   // [2,E] (src row then dst row)
  const float* W    = (const float*)d_in[2];
  const float* attn = (const float*)d_in[3];
  const float* ow   = (const float*)d_in[4];
  const float* ob   = (const float*)d_in[5];
  const int n = in_sizes[0] / 128;            // 50000 (< 65536: u32 edge pack)
  const int E = in_sizes[1] / 2;
  float* out = (float*)d_out;

  char* wp = (char*)d_ws;
  auto alloc = [&](size_t bytes) {
    char* p = wp;
    wp += (bytes + 255) & ~(size_t)255;
    return p;
  };
  unsigned short* wf  = (unsigned short*)alloc(2048 * 8 * 2);
  unsigned short* owf = (unsigned short*)alloc(2048 * 8 * 2);
  unsigned int*   Wxb = (unsigned int*)alloc((size_t)n * 64 * 4);
  float* s_i    = (float*)alloc((size_t)n * 4 * 4);
  float* s_j    = (float*)alloc((size_t)n * 4 * 4);
  int*   gcnt   = (int*)alloc(256 * 4);
  int*   gcur   = (int*)alloc(256 * 4);
  int*   offs   = (int*)alloc((size_t)n * 4);
  int*   cnts   = (int*)alloc((size_t)n * 4);
  unsigned int* tmp = (unsigned int*)alloc((size_t)E * 4);
  int*   csr    = (int*)alloc((size_t)E * 4);

  dim3 blk(256);
  const int NB = (n + 255) / 256;                            // node buckets (196)
  const int EB = (E + 256 * BIN_VPT - 1) / (256 * BIN_VPT);  // edge blocks (196)
  const int strips = (n + 15) / 16;
  const int gemmBlocks = (strips + 3) / 4;

  k_setup<<<16, blk, 0, stream>>>(W, ow, wf, owf, gcnt, gcur);
  k_gemm1b<<<gemmBlocks + EB, blk, 0, stream>>>(x, wf, attn, Wxb, s_i, s_j, n,
                                                edges + E, gcnt, E, gemmBlocks);
  k_bin1<<<EB, blk, 0, stream>>>(edges, gcnt, gcur, tmp, E);
  k_bin2<<<NB, blk, 0, stream>>>(tmp, gcnt, csr, offs, cnts, n);
  k_aggm<<<(n + 15) / 16, blk, 0, stream>>>(Wxb, s_i, s_j, offs, cnts, csr,
                                            owf, ob, out, n);
}

// Round 13
// 102.734 us; speedup vs baseline: 1.6891x; 1.0574x over previous
//
#include <hip/hip_runtime.h>
#include <math.h>

// GAT layer: N=50000 nodes, E=800000 edges, D_IN=D_OUT=128, H=4, D_H=32
//
// 5-dispatch pipeline (round-7 structure, proven 96.2 us):
//   k_setup  : pack W / out_w into bf16 MFMA B-fragments + zero gcnt/gcur
//   k_gemm1b : Wx(bf16) = x @ W via MFMA + fused attention scores s_i/s_j;
//              trailing blocks do the dst-bucket histogram (bucket = dst>>8)
//   k_bin1   : block-local counting sort -> bucket-contiguous tmp (VPT=8)
//   k_bin2   : one block per bucket: node counts + scan (emits offs/cnts) +
//              placement — all scatter block-private
//   k_aggm   : 4 waves/block, 4 consecutive nodes per wave. Staging: 64 edges
//              lane-parallel (csr + s_i gather + exp) -> LDS. Consumer: full
//              256B row per wave instruction, 8 rows in flight. Phase 2:
//              output GEMM (MFMA) + bias + ELU from the LDS tile.
//
// k_aggm history (rounds 7-12): pexp-precompute, 2-edge split, 4-edge split,
// column-split, reg-dbuf ALL regressed vs this plain form — it sits at
// ~4.7 TB/s effective on the random row gather (~74% of streaming peak).

typedef __attribute__((ext_vector_type(8))) short short8;
typedef __attribute__((ext_vector_type(4))) float f32x4;

#define BIN_VPT 8           // edges per thread; 2048 edges per 256-thread block

__device__ __forceinline__ float lrelu(float v) { return v >= 0.f ? v : 0.2f * v; }

__device__ __forceinline__ unsigned short f2bf(float f) {  // RNE f32 -> bf16
  unsigned int u = __float_as_uint(f);
  u += 0x7FFFu + ((u >> 16) & 1u);
  return (unsigned short)(u >> 16);
}
// HW packed RNE convert: dst = bf16(lo) | bf16(hi)<<16
__device__ __forceinline__ unsigned int cvt_pk_bf16(float lo, float hi) {
  unsigned int r;
  asm("v_cvt_pk_bf16_f32 %0, %1, %2" : "=v"(r) : "v"(lo), "v"(hi));
  return r;
}
__device__ __forceinline__ float bflo(unsigned int w) { return __uint_as_float(w << 16); }
__device__ __forceinline__ float bfhi(unsigned int w) { return __uint_as_float(w & 0xFFFF0000u); }

// 256-thread exclusive scan helper (value v per thread -> returns excl; ws[4] LDS)
__device__ __forceinline__ int blk_excl_scan(int v, int* ws) {
  const int t = threadIdx.x, lane = t & 63, wv = t >> 6;
  int incl = v;
#pragma unroll
  for (int m = 1; m < 64; m <<= 1) {
    int x = __shfl_up(incl, m, 64);
    if (lane >= m) incl += x;
  }
  if (lane == 63) ws[wv] = incl;
  __syncthreads();
  int woff = 0;
  for (int p = 0; p < wv; ++p) woff += ws[p];
  return woff + incl - v;
}

// ---------------------------------------------------------------- setup
__global__ void k_setup(const float* __restrict__ W, const float* __restrict__ ow,
                        unsigned short* __restrict__ wf, unsigned short* __restrict__ owf,
                        int* __restrict__ gcnt, int* __restrict__ gcur) {
  const int t = blockIdx.x * 256 + threadIdx.x;
  if (blockIdx.x == 0) gcnt[threadIdx.x] = 0;
  if (blockIdx.x == 1) gcur[threadIdx.x] = 0;
  const int which = t >> 11;           // 0: W, 1: out_w
  const int tt = t & 2047;
  const float* M = which ? ow : W;
  unsigned short* F = which ? owf : wf;
  const int lane = tt & 63;
  const int nt = (tt >> 6) & 7;
  const int ks = tt >> 9;
  const int k0 = ks * 32 + (lane >> 4) * 8;
  const int col = nt * 16 + (lane & 15);
  short8 v;
#pragma unroll
  for (int j = 0; j < 8; ++j) v[j] = (short)f2bf(M[(k0 + j) * 128 + col]);
  *(short8*)(F + (size_t)tt * 8) = v;
}

// ---------------------------------------------------------------- GEMM1 + hist
__global__ void k_gemm1b(const float* __restrict__ x, const unsigned short* __restrict__ wf,
                         const float* __restrict__ attn, unsigned int* __restrict__ Wxb,
                         float* __restrict__ s_i, float* __restrict__ s_j, int n,
                         const int* __restrict__ dst, int* __restrict__ gcnt, int E,
                         int gemmBlocks) {
  __shared__ int lc[256];
  if (blockIdx.x >= gemmBlocks) {  // ---- histogram part
    const int bb = blockIdx.x - gemmBlocks;
    lc[threadIdx.x] = 0;
    __syncthreads();
    const int base = bb * (256 * BIN_VPT);
#pragma unroll
    for (int j = 0; j < BIN_VPT; ++j) {
      int e = base + j * 256 + threadIdx.x;
      if (e < E) atomicAdd(&lc[((unsigned int)dst[e]) >> 8], 1);
    }
    __syncthreads();
    int c = lc[threadIdx.x];
    if (c) atomicAdd(&gcnt[threadIdx.x], c);
    return;
  }

  // ---- GEMM part: one wave = 16-row strip, acc[nt] covers cols nt*16..+15
  const int lane = threadIdx.x & 63;
  const int gw = blockIdx.x * (blockDim.x >> 6) + (threadIdx.x >> 6);
  const int r0 = gw * 16;
  if (r0 >= n) return;
  const int g = lane >> 4, c = lane & 15;

  f32x4 acc[8];
#pragma unroll
  for (int nt = 0; nt < 8; ++nt) acc[nt] = (f32x4){0.f, 0.f, 0.f, 0.f};

  const int arow = min(r0 + c, n - 1);
#pragma unroll
  for (int ks = 0; ks < 4; ++ks) {
    const float* xr = x + (size_t)arow * 128 + ks * 32 + g * 8;
    float4 v0 = *(const float4*)xr;
    float4 v1 = *(const float4*)(xr + 4);
    uint4 au;
    au.x = cvt_pk_bf16(v0.x, v0.y);
    au.y = cvt_pk_bf16(v0.z, v0.w);
    au.z = cvt_pk_bf16(v1.x, v1.y);
    au.w = cvt_pk_bf16(v1.z, v1.w);
    short8 af = __builtin_bit_cast(short8, au);
#pragma unroll
    for (int nt = 0; nt < 8; ++nt) {
      short8 bf = *(const short8*)(wf + ((size_t)(ks * 8 + nt) * 64 + lane) * 8);
      acc[nt] = __builtin_amdgcn_mfma_f32_16x16x32_bf16(af, bf, acc[nt], 0, 0, 0);
    }
  }

  const int odd = c & 1;
#pragma unroll
  for (int r = 0; r < 4; ++r) {
    const int row = r0 + g * 4 + r;
    if (row >= n) continue;
    unsigned int* dp = Wxb + (size_t)row * 64;
#pragma unroll
    for (int ntp = 0; ntp < 4; ++ntp) {
      float ve = acc[ntp][r], vo = acc[ntp + 4][r];
      float vex = __shfl_xor(ve, 1, 64);
      float vox = __shfl_xor(vo, 1, 64);
      const int nt = odd ? ntp + 4 : ntp;
      dp[nt * 8 + (c >> 1)] = cvt_pk_bf16(odd ? vox : ve, odd ? vo : vex);
    }
  }

  float aiv[8], ajv[8];
#pragma unroll
  for (int nt = 0; nt < 8; ++nt) {
    const int hh = nt >> 1, ch = (nt & 1) * 16 + c;
    aiv[nt] = attn[hh * 64 + ch];
    ajv[nt] = attn[hh * 64 + 32 + ch];
  }
#pragma unroll
  for (int r = 0; r < 4; ++r) {
    float pih[4], pjh[4];
#pragma unroll
    for (int h = 0; h < 4; ++h) {
      pih[h] = acc[2 * h][r] * aiv[2 * h] + acc[2 * h + 1][r] * aiv[2 * h + 1];
      pjh[h] = acc[2 * h][r] * ajv[2 * h] + acc[2 * h + 1][r] * ajv[2 * h + 1];
    }
#pragma unroll
    for (int m = 1; m < 16; m <<= 1) {
#pragma unroll
      for (int h = 0; h < 4; ++h) {
        pih[h] += __shfl_xor(pih[h], m, 64);
        pjh[h] += __shfl_xor(pjh[h], m, 64);
      }
    }
    const int row = r0 + g * 4 + r;
    if (c == 0 && row < n) {
#pragma unroll
      for (int h = 0; h < 4; ++h) {
        s_i[(size_t)row * 4 + h] = pih[h];
        s_j[(size_t)row * 4 + h] = pjh[h];
      }
    }
  }
}

// ---------------------------------------------------------------- bin1
__global__ void k_bin1(const int* __restrict__ edges, const int* __restrict__ gcnt,
                       int* __restrict__ gcur, unsigned int* __restrict__ tmp, int E) {
  __shared__ int ws[4];
  __shared__ int bst_s[256];
  __shared__ int lcnt[256];
  __shared__ int lbase[256];
  const int t = threadIdx.x;
  const int excl = blk_excl_scan(gcnt[t], ws);
  bst_s[t] = excl;
  lcnt[t] = 0;
  __syncthreads();
  const int base = blockIdx.x * (256 * BIN_VPT);
  unsigned int pv[BIN_VPT];
  int rk[BIN_VPT];
#pragma unroll
  for (int j = 0; j < BIN_VPT; ++j) {
    int e = base + j * 256 + t;
    if (e < E) {
      unsigned int s = (unsigned int)edges[e];
      unsigned int d = (unsigned int)edges[E + e];
      pv[j] = s | (d << 16);
      rk[j] = atomicAdd(&lcnt[d >> 8], 1);
    } else {
      pv[j] = 0u;
      rk[j] = -1;
    }
  }
  __syncthreads();
  const int c = lcnt[t];
  lbase[t] = bst_s[t] + (c ? atomicAdd(&gcur[t], c) : 0);
  __syncthreads();
#pragma unroll
  for (int j = 0; j < BIN_VPT; ++j) {
    if (rk[j] >= 0) {
      const int b = pv[j] >> 24;  // dst >> 8
      tmp[lbase[b] + rk[j]] = pv[j];
    }
  }
}

// ---------------------------------------------------------------- bin2
__global__ void k_bin2(const unsigned int* __restrict__ tmp, const int* __restrict__ gcnt,
                       int* __restrict__ csr, int* __restrict__ offs,
                       int* __restrict__ cnts, int n) {
  __shared__ int ws[4];
  __shared__ int bst_s[256];
  __shared__ int nc[256];
  const int b = blockIdx.x;
  const int t = threadIdx.x;
  bst_s[t] = blk_excl_scan(gcnt[t], ws);
  nc[t] = 0;
  __syncthreads();
  const int base = bst_s[b], cnt = gcnt[b];
  for (int i = t; i < cnt; i += 256)
    atomicAdd(&nc[(tmp[base + i] >> 16) & 255], 1);
  __syncthreads();
  const int node = b * 256 + t;
  const int c = nc[t];
  if (node < n) cnts[node] = c;
  __syncthreads();           // blk_excl_scan reuses ws; ensure count phase done
  const int excl = blk_excl_scan(c, ws);
  if (node < n) offs[node] = base + excl;
  __syncthreads();           // everyone done reading nc from count phase
  nc[t] = excl;              // becomes local cursor
  __syncthreads();
  for (int i = t; i < cnt; i += 256) {
    unsigned int v = tmp[base + i];
    int pos = atomicAdd(&nc[(v >> 16) & 255], 1);
    csr[base + pos] = (int)(v & 0xFFFFu);
  }
}

// ---------------------------------------------------------------- agg + GEMM2
// 4 waves/block (256 thr), 16 nodes/block, 4 consecutive nodes per wave.
#define AGG_EDGE(e)                                                     \
  {                                                                     \
    int s_ = lsrc[wv][e];                                               \
    float p_ = lp[wv][e][h];                                            \
    unsigned int w_ = Wxb[(unsigned)(s_ << 6) | (unsigned)lane];        \
    acc.x += p_ * bflo(w_);                                             \
    acc.y += p_ * bfhi(w_);                                             \
    smh += p_;                                                          \
  }

__global__ void k_aggm(const unsigned int* __restrict__ Wxb, const float* __restrict__ s_i,
                       const float* __restrict__ s_j, const int* __restrict__ offs,
                       const int* __restrict__ cnts, const int* __restrict__ csr_src,
                       const unsigned short* __restrict__ owf, const float* __restrict__ ob,
                       float* __restrict__ out, int n) {
  __shared__ unsigned int aTile[16][65];
  __shared__ int   lsrc[4][64];
  __shared__ float lp[4][64][4];
  const int lane = threadIdx.x & 63;
  const int wv = threadIdx.x >> 6;
  const int nd0 = blockIdx.x * 16;
  const int nd0w = nd0 + wv * 4;       // first of this wave's 4 nodes
  const int h = lane >> 4;

  // per-node degrees in lanes 0..3; boundaries b0<b1<b2 within the wave span
  int degv = 0;
  if (lane < 4 && nd0w + lane < n) degv = cnts[nd0w + lane];
  const int wbase = (nd0w < n) ? offs[nd0w] : 0;
  const int d0 = __shfl(degv, 0, 64), d1 = __shfl(degv, 1, 64);
  const int d2 = __shfl(degv, 2, 64), d3 = __shfl(degv, 3, 64);
  const int b0 = d0, b1 = d0 + d1, b2 = b1 + d2;
  const int tot = b2 + d3;

  int cur = 0;
  int rem = d0;
  float2 acc = make_float2(0.f, 0.f);
  float smh = 0.f;

  // leading zero-degree nodes
  while (cur < 4 && rem == 0) {
    if (nd0w + cur < n) aTile[(wv << 2) + cur][lane] = 0u;  // agg row = 0
    ++cur;
    rem = (cur == 1) ? d1 : (cur == 2) ? d2 : (cur == 3) ? d3 : 0;
  }

  for (int c0 = 0; c0 < tot; c0 += 64) {
    const int m = min(64, tot - c0);
    if (lane < m) {
      const int pos = c0 + lane;
      const int src = csr_src[wbase + pos];
      const int nl = (pos >= b0) + (pos >= b1) + (pos >= b2);
      const float4 sj = *(const float4*)(s_j + (size_t)(nd0w + nl) * 4);
      const float4 si = *(const float4*)(s_i + (size_t)src * 4);
      float4 p;
      p.x = __expf(lrelu(si.x + sj.x));
      p.y = __expf(lrelu(si.y + sj.y));
      p.z = __expf(lrelu(si.z + sj.z));
      p.w = __expf(lrelu(si.w + sj.w));
      lsrc[wv][lane] = src;
      *(float4*)&lp[wv][lane][0] = p;
    }
    asm volatile("s_waitcnt lgkmcnt(0)" ::: "memory");  // same-wave LDS RAW
    int k = 0;
    while (k < m) {
      const int take = min(m - k, rem);
      int e = k;
      const int end = k + take;
      for (; e + 8 <= end; e += 8) {  // 8 independent 256B row loads in flight
        AGG_EDGE(e + 0) AGG_EDGE(e + 1) AGG_EDGE(e + 2) AGG_EDGE(e + 3)
        AGG_EDGE(e + 4) AGG_EDGE(e + 5) AGG_EDGE(e + 6) AGG_EDGE(e + 7)
      }
      for (; e + 4 <= end; e += 4) {
        AGG_EDGE(e + 0) AGG_EDGE(e + 1) AGG_EDGE(e + 2) AGG_EDGE(e + 3)
      }
      for (; e < end; ++e) AGG_EDGE(e)
      k += take;
      rem -= take;
      while (rem == 0 && cur < 4) {  // finalize node(s); skip zero-deg
        const float inv = 1.f / (smh + 1e-16f);
        if (nd0w + cur < n)
          aTile[(wv << 2) + cur][lane] = cvt_pk_bf16(acc.x * inv, acc.y * inv);
        ++cur;
        acc.x = 0.f; acc.y = 0.f; smh = 0.f;
        rem = (cur == 1) ? d1 : (cur == 2) ? d2 : (cur == 3) ? d3 : 0;
      }
      if (cur >= 4) break;
    }
  }
  __syncthreads();

  // ---- phase 2: out-GEMM on the 16-row tile; each wave does 2 col-tiles
  const int g = lane >> 4, c = lane & 15;
#pragma unroll
  for (int t2 = 0; t2 < 2; ++t2) {
    const int nt = wv + t2 * 4;
    f32x4 o = (f32x4){0.f, 0.f, 0.f, 0.f};
#pragma unroll
    for (int ks = 0; ks < 4; ++ks) {
      uint4 au = *(const uint4*)&aTile[c][ks * 16 + g * 4];  // A row = lane&15
      short8 af = __builtin_bit_cast(short8, au);
      short8 bf = *(const short8*)(owf + ((size_t)(ks * 8 + nt) * 64 + lane) * 8);
      o = __builtin_amdgcn_mfma_f32_16x16x32_bf16(af, bf, o, 0, 0, 0);
    }
#pragma unroll
    for (int r = 0; r < 4; ++r) {
      const int row = nd0 + g * 4 + r;   // D row = (lane>>4)*4 + r
      if (row < n) {
        float v = o[r] + ob[nt * 16 + c];
        v = v > 0.f ? v : expm1f(v);
        out[(size_t)row * 128 + nt * 16 + c] = v;
      }
    }
  }
}

// ---------------------------------------------------------------- launch
extern "C" void kernel_launch(void* const* d_in, const int* in_sizes, int n_in,
                              void* d_out, int out_size, void* d_ws, size_t ws_size,
                              hipStream_t stream) {
  const float* x    = (const float*)d_in[0];
  const int*   edges = (const int*)d_in[1];   // [2,E] (src row then dst row)
  const float* W    = (const float*)d_in[2];
  const float* attn = (const float*)d_in[3];
  const float* ow   = (const float*)d_in[4];
  const float* ob   = (const float*)d_in[5];
  const int n = in_sizes[0] / 128;            // 50000 (< 65536: u32 edge pack)
  const int E = in_sizes[1] / 2;
  float* out = (float*)d_out;

  char* wp = (char*)d_ws;
  auto alloc = [&](size_t bytes) {
    char* p = wp;
    wp += (bytes + 255) & ~(size_t)255;
    return p;
  };
  unsigned short* wf  = (unsigned short*)alloc(2048 * 8 * 2);
  unsigned short* owf = (unsigned short*)alloc(2048 * 8 * 2);
  unsigned int*   Wxb = (unsigned int*)alloc((size_t)n * 64 * 4);
  float* s_i    = (float*)alloc((size_t)n * 4 * 4);
  float* s_j    = (float*)alloc((size_t)n * 4 * 4);
  int*   gcnt   = (int*)alloc(256 * 4);
  int*   gcur   = (int*)alloc(256 * 4);
  int*   offs   = (int*)alloc((size_t)n * 4);
  int*   cnts   = (int*)alloc((size_t)n * 4);
  unsigned int* tmp = (unsigned int*)alloc((size_t)E * 4);
  int*   csr    = (int*)alloc((size_t)E * 4);

  dim3 blk(256);
  const int NB = (n + 255) / 256;                            // node buckets (196)
  const int EB = (E + 256 * BIN_VPT - 1) / (256 * BIN_VPT);  // edge blocks (391)
  const int strips = (n + 15) / 16;
  const int gemmBlocks = (strips + 3) / 4;

  k_setup<<<16, blk, 0, stream>>>(W, ow, wf, owf, gcnt, gcur);
  k_gemm1b<<<gemmBlocks + EB, blk, 0, stream>>>(x, wf, attn, Wxb, s_i, s_j, n,
                                                edges + E, gcnt, E, gemmBlocks);
  k_bin1<<<EB, blk, 0, stream>>>(edges, gcnt, gcur, tmp, E);
  k_bin2<<<NB, blk, 0, stream>>>(tmp, gcnt, csr, offs, cnts, n);
  k_aggm<<<(n + 15) / 16, blk, 0, stream>>>(Wxb, s_i, s_j, offs, cnts, csr,
                                            owf, ob, out, n);
}

// Round 14
// 93.303 us; speedup vs baseline: 1.8598x; 1.1011x over previous
//
#include <hip/hip_runtime.h>
#include <math.h>

// GAT layer: N=50000 nodes, E=800000 edges, D_IN=D_OUT=128, H=4, D_H=32
//
// 5-dispatch pipeline (round-7 structure; BIN_VPT=16):
//   k_setup  : pack W / out_w into bf16 MFMA B-fragments + zero gcnt/gcur;
//              extra block computes Mw = W @ att_full (128x16: cols 0-3 a_i
//              heads, 4-7 a_j heads) and packs it as bf16 B-fragments so
//              s_i/s_j = x @ Mw rides the gemm1 MFMA (associativity).
//   k_gemm1b : Wx(bf16) = x @ W via MFMA; s_i/s_j via ONE extra MFMA per
//              ks (replaces the 128-shfl epilogue); trailing blocks do the
//              dst-bucket histogram (bucket = dst>>8)
//   k_bin1   : block-local counting sort -> bucket-contiguous tmp
//   k_bin2   : one block per bucket: node counts + scan (offs/cnts) +
//              placement — all scatter block-private
//   k_aggm   : 4 waves/block, 4 consecutive nodes per wave; LDS-staged
//              (csr + s_i gather + exp); consumer = full 256B row per wave
//              instruction, 8 in flight. Phase 2: out-GEMM + bias + ELU.
//              (At ~4.7 TB/s effective random gather — measured floor over
//              6 structural variants, rounds 7-12.)

typedef __attribute__((ext_vector_type(8))) short short8;
typedef __attribute__((ext_vector_type(4))) float f32x4;

#define BIN_VPT 16          // edges per thread; 4096 edges per 256-thread block

__device__ __forceinline__ float lrelu(float v) { return v >= 0.f ? v : 0.2f * v; }

__device__ __forceinline__ unsigned short f2bf(float f) {  // RNE f32 -> bf16
  unsigned int u = __float_as_uint(f);
  u += 0x7FFFu + ((u >> 16) & 1u);
  return (unsigned short)(u >> 16);
}
// HW packed RNE convert: dst = bf16(lo) | bf16(hi)<<16
__device__ __forceinline__ unsigned int cvt_pk_bf16(float lo, float hi) {
  unsigned int r;
  asm("v_cvt_pk_bf16_f32 %0, %1, %2" : "=v"(r) : "v"(lo), "v"(hi));
  return r;
}
__device__ __forceinline__ float bflo(unsigned int w) { return __uint_as_float(w << 16); }
__device__ __forceinline__ float bfhi(unsigned int w) { return __uint_as_float(w & 0xFFFF0000u); }

// 256-thread exclusive scan helper (value v per thread -> returns excl; ws[4] LDS)
__device__ __forceinline__ int blk_excl_scan(int v, int* ws) {
  const int t = threadIdx.x, lane = t & 63, wv = t >> 6;
  int incl = v;
#pragma unroll
  for (int m = 1; m < 64; m <<= 1) {
    int x = __shfl_up(incl, m, 64);
    if (lane >= m) incl += x;
  }
  if (lane == 63) ws[wv] = incl;
  __syncthreads();
  int woff = 0;
  for (int p = 0; p < wv; ++p) woff += ws[p];
  return woff + incl - v;
}

// ---------------------------------------------------------------- setup
// blocks 0..7: W fragments; 8..15: out_w fragments; block 16: Mw fragments.
// blocks 0/1 zero gcnt/gcur.
__global__ void k_setup(const float* __restrict__ W, const float* __restrict__ ow,
                        const float* __restrict__ attn,
                        unsigned short* __restrict__ wf, unsigned short* __restrict__ owf,
                        unsigned short* __restrict__ abf,
                        int* __restrict__ gcnt, int* __restrict__ gcur) {
  __shared__ float Mw[128][16];
  if (blockIdx.x == 16) {
    // ---- compute Mw = W @ att_full in f32 (LDS), then pack bf16 fragments
    const int t = threadIdx.x;
    if (t < 128) {
      float v[16];
#pragma unroll
      for (int c = 0; c < 16; ++c) v[c] = 0.f;
#pragma unroll
      for (int h = 0; h < 4; ++h) {
        float si = 0.f, sj = 0.f;
        for (int dd = 0; dd < 32; ++dd) {
          const float w = W[t * 128 + h * 32 + dd];
          si += w * attn[h * 64 + dd];
          sj += w * attn[h * 64 + 32 + dd];
        }
        v[h] = si;
        v[4 + h] = sj;
      }
#pragma unroll
      for (int c = 0; c < 16; ++c) Mw[t][c] = v[c];
    }
    __syncthreads();
    const int lane = t & 63;
    const int ks = t >> 6;                 // 0..3
    const int k0 = ks * 32 + (lane >> 4) * 8;
    const int col = lane & 15;
    short8 vv;
#pragma unroll
    for (int j = 0; j < 8; ++j) vv[j] = (short)f2bf(Mw[k0 + j][col]);
    *(short8*)(abf + ((size_t)(ks * 64 + lane)) * 8) = vv;
    return;
  }
  const int t = blockIdx.x * 256 + threadIdx.x;
  if (blockIdx.x == 0) gcnt[threadIdx.x] = 0;
  if (blockIdx.x == 1) gcur[threadIdx.x] = 0;
  const int which = t >> 11;           // 0: W, 1: out_w
  const int tt = t & 2047;
  const float* M = which ? ow : W;
  unsigned short* F = which ? owf : wf;
  const int lane = tt & 63;
  const int nt = (tt >> 6) & 7;
  const int ks = tt >> 9;
  const int k0 = ks * 32 + (lane >> 4) * 8;
  const int col = nt * 16 + (lane & 15);
  short8 v;
#pragma unroll
  for (int j = 0; j < 8; ++j) v[j] = (short)f2bf(M[(k0 + j) * 128 + col]);
  *(short8*)(F + (size_t)tt * 8) = v;
}

// ---------------------------------------------------------------- GEMM1 + hist
__global__ void k_gemm1b(const float* __restrict__ x, const unsigned short* __restrict__ wf,
                         const unsigned short* __restrict__ abf,
                         unsigned int* __restrict__ Wxb,
                         float* __restrict__ s_i, float* __restrict__ s_j, int n,
                         const int* __restrict__ dst, int* __restrict__ gcnt, int E,
                         int gemmBlocks) {
  __shared__ int lc[256];
  if (blockIdx.x >= gemmBlocks) {  // ---- histogram part
    const int bb = blockIdx.x - gemmBlocks;
    lc[threadIdx.x] = 0;
    __syncthreads();
    const int base = bb * (256 * BIN_VPT);
#pragma unroll
    for (int j = 0; j < BIN_VPT; ++j) {
      int e = base + j * 256 + threadIdx.x;
      if (e < E) atomicAdd(&lc[((unsigned int)dst[e]) >> 8], 1);
    }
    __syncthreads();
    int c = lc[threadIdx.x];
    if (c) atomicAdd(&gcnt[threadIdx.x], c);
    return;
  }

  // ---- GEMM part: one wave = 16-row strip, acc[nt] covers cols nt*16..+15
  const int lane = threadIdx.x & 63;
  const int gw = blockIdx.x * (blockDim.x >> 6) + (threadIdx.x >> 6);
  const int r0 = gw * 16;
  if (r0 >= n) return;
  const int g = lane >> 4, c = lane & 15;

  f32x4 acc[8];
#pragma unroll
  for (int nt = 0; nt < 8; ++nt) acc[nt] = (f32x4){0.f, 0.f, 0.f, 0.f};
  f32x4 sacc = (f32x4){0.f, 0.f, 0.f, 0.f};

  const int arow = min(r0 + c, n - 1);
#pragma unroll
  for (int ks = 0; ks < 4; ++ks) {
    const float* xr = x + (size_t)arow * 128 + ks * 32 + g * 8;
    float4 v0 = *(const float4*)xr;
    float4 v1 = *(const float4*)(xr + 4);
    uint4 au;
    au.x = cvt_pk_bf16(v0.x, v0.y);
    au.y = cvt_pk_bf16(v0.z, v0.w);
    au.z = cvt_pk_bf16(v1.x, v1.y);
    au.w = cvt_pk_bf16(v1.z, v1.w);
    short8 af = __builtin_bit_cast(short8, au);
#pragma unroll
    for (int nt = 0; nt < 8; ++nt) {
      short8 bf = *(const short8*)(wf + ((size_t)(ks * 8 + nt) * 64 + lane) * 8);
      acc[nt] = __builtin_amdgcn_mfma_f32_16x16x32_bf16(af, bf, acc[nt], 0, 0, 0);
    }
    // s_i/s_j: one extra MFMA per ks (B = Mw fragments)
    short8 ab = *(const short8*)(abf + ((size_t)(ks * 64 + lane)) * 8);
    sacc = __builtin_amdgcn_mfma_f32_16x16x32_bf16(af, ab, sacc, 0, 0, 0);
  }

  const int odd = c & 1;
#pragma unroll
  for (int r = 0; r < 4; ++r) {
    const int row = r0 + g * 4 + r;
    if (row >= n) continue;
    unsigned int* dp = Wxb + (size_t)row * 64;
#pragma unroll
    for (int ntp = 0; ntp < 4; ++ntp) {
      float ve = acc[ntp][r], vo = acc[ntp + 4][r];
      float vex = __shfl_xor(ve, 1, 64);
      float vox = __shfl_xor(vo, 1, 64);
      const int nt = odd ? ntp + 4 : ntp;
      dp[nt * 8 + (c >> 1)] = cvt_pk_bf16(odd ? vox : ve, odd ? vo : vex);
    }
  }

  // s write: D(lane,r) -> row=(lane>>4)*4+r, col=lane&15; cols 0-3 = s_i
  // heads, 4-7 = s_j heads.
#pragma unroll
  for (int r = 0; r < 4; ++r) {
    const int row = r0 + g * 4 + r;
    if (row < n) {
      if (c < 4)      s_i[(size_t)row * 4 + c] = sacc[r];
      else if (c < 8) s_j[(size_t)row * 4 + (c - 4)] = sacc[r];
    }
  }
}

// ---------------------------------------------------------------- bin1
__global__ void k_bin1(const int* __restrict__ edges, const int* __restrict__ gcnt,
                       int* __restrict__ gcur, unsigned int* __restrict__ tmp, int E) {
  __shared__ int ws[4];
  __shared__ int bst_s[256];
  __shared__ int lcnt[256];
  __shared__ int lbase[256];
  const int t = threadIdx.x;
  const int excl = blk_excl_scan(gcnt[t], ws);
  bst_s[t] = excl;
  lcnt[t] = 0;
  __syncthreads();
  const int base = blockIdx.x * (256 * BIN_VPT);
  unsigned int pv[BIN_VPT];
  int rk[BIN_VPT];
#pragma unroll
  for (int j = 0; j < BIN_VPT; ++j) {
    int e = base + j * 256 + t;
    if (e < E) {
      unsigned int s = (unsigned int)edges[e];
      unsigned int d = (unsigned int)edges[E + e];
      pv[j] = s | (d << 16);
      rk[j] = atomicAdd(&lcnt[d >> 8], 1);
    } else {
      pv[j] = 0u;
      rk[j] = -1;
    }
  }
  __syncthreads();
  const int c = lcnt[t];
  lbase[t] = bst_s[t] + (c ? atomicAdd(&gcur[t], c) : 0);
  __syncthreads();
#pragma unroll
  for (int j = 0; j < BIN_VPT; ++j) {
    if (rk[j] >= 0) {
      const int b = pv[j] >> 24;  // dst >> 8
      tmp[lbase[b] + rk[j]] = pv[j];
    }
  }
}

// ---------------------------------------------------------------- bin2
__global__ void k_bin2(const unsigned int* __restrict__ tmp, const int* __restrict__ gcnt,
                       int* __restrict__ csr, int* __restrict__ offs,
                       int* __restrict__ cnts, int n) {
  __shared__ int ws[4];
  __shared__ int bst_s[256];
  __shared__ int nc[256];
  const int b = blockIdx.x;
  const int t = threadIdx.x;
  bst_s[t] = blk_excl_scan(gcnt[t], ws);
  nc[t] = 0;
  __syncthreads();
  const int base = bst_s[b], cnt = gcnt[b];
  for (int i = t; i < cnt; i += 256)
    atomicAdd(&nc[(tmp[base + i] >> 16) & 255], 1);
  __syncthreads();
  const int node = b * 256 + t;
  const int c = nc[t];
  if (node < n) cnts[node] = c;
  __syncthreads();           // blk_excl_scan reuses ws; ensure count phase done
  const int excl = blk_excl_scan(c, ws);
  if (node < n) offs[node] = base + excl;
  __syncthreads();           // everyone done reading nc from count phase
  nc[t] = excl;              // becomes local cursor
  __syncthreads();
  for (int i = t; i < cnt; i += 256) {
    unsigned int v = tmp[base + i];
    int pos = atomicAdd(&nc[(v >> 16) & 255], 1);
    csr[base + pos] = (int)(v & 0xFFFFu);
  }
}

// ---------------------------------------------------------------- agg + GEMM2
// 4 waves/block (256 thr), 16 nodes/block, 4 consecutive nodes per wave.
#define AGG_EDGE(e)                                                     \
  {                                                                     \
    int s_ = lsrc[wv][e];                                               \
    float p_ = lp[wv][e][h];                                            \
    unsigned int w_ = Wxb[(unsigned)(s_ << 6) | (unsigned)lane];        \
    acc.x += p_ * bflo(w_);                                             \
    acc.y += p_ * bfhi(w_);                                             \
    smh += p_;                                                          \
  }

__global__ void k_aggm(const unsigned int* __restrict__ Wxb, const float* __restrict__ s_i,
                       const float* __restrict__ s_j, const int* __restrict__ offs,
                       const int* __restrict__ cnts, const int* __restrict__ csr_src,
                       const unsigned short* __restrict__ owf, const float* __restrict__ ob,
                       float* __restrict__ out, int n) {
  __shared__ unsigned int aTile[16][65];
  __shared__ int   lsrc[4][64];
  __shared__ float lp[4][64][4];
  const int lane = threadIdx.x & 63;
  const int wv = threadIdx.x >> 6;
  const int nd0 = blockIdx.x * 16;
  const int nd0w = nd0 + wv * 4;       // first of this wave's 4 nodes
  const int h = lane >> 4;

  // per-node degrees in lanes 0..3; boundaries b0<b1<b2 within the wave span
  int degv = 0;
  if (lane < 4 && nd0w + lane < n) degv = cnts[nd0w + lane];
  const int wbase = (nd0w < n) ? offs[nd0w] : 0;
  const int d0 = __shfl(degv, 0, 64), d1 = __shfl(degv, 1, 64);
  const int d2 = __shfl(degv, 2, 64), d3 = __shfl(degv, 3, 64);
  const int b0 = d0, b1 = d0 + d1, b2 = b1 + d2;
  const int tot = b2 + d3;

  int cur = 0;
  int rem = d0;
  float2 acc = make_float2(0.f, 0.f);
  float smh = 0.f;

  // leading zero-degree nodes
  while (cur < 4 && rem == 0) {
    if (nd0w + cur < n) aTile[(wv << 2) + cur][lane] = 0u;  // agg row = 0
    ++cur;
    rem = (cur == 1) ? d1 : (cur == 2) ? d2 : (cur == 3) ? d3 : 0;
  }

  for (int c0 = 0; c0 < tot; c0 += 64) {
    const int m = min(64, tot - c0);
    if (lane < m) {
      const int pos = c0 + lane;
      const int src = csr_src[wbase + pos];
      const int nl = (pos >= b0) + (pos >= b1) + (pos >= b2);
      const float4 sj = *(const float4*)(s_j + (size_t)(nd0w + nl) * 4);
      const float4 si = *(const float4*)(s_i + (size_t)src * 4);
      float4 p;
      p.x = __expf(lrelu(si.x + sj.x));
      p.y = __expf(lrelu(si.y + sj.y));
      p.z = __expf(lrelu(si.z + sj.z));
      p.w = __expf(lrelu(si.w + sj.w));
      lsrc[wv][lane] = src;
      *(float4*)&lp[wv][lane][0] = p;
    }
    asm volatile("s_waitcnt lgkmcnt(0)" ::: "memory");  // same-wave LDS RAW
    int k = 0;
    while (k < m) {
      const int take = min(m - k, rem);
      int e = k;
      const int end = k + take;
      for (; e + 8 <= end; e += 8) {  // 8 independent 256B row loads in flight
        AGG_EDGE(e + 0) AGG_EDGE(e + 1) AGG_EDGE(e + 2) AGG_EDGE(e + 3)
        AGG_EDGE(e + 4) AGG_EDGE(e + 5) AGG_EDGE(e + 6) AGG_EDGE(e + 7)
      }
      for (; e + 4 <= end; e += 4) {
        AGG_EDGE(e + 0) AGG_EDGE(e + 1) AGG_EDGE(e + 2) AGG_EDGE(e + 3)
      }
      for (; e < end; ++e) AGG_EDGE(e)
      k += take;
      rem -= take;
      while (rem == 0 && cur < 4) {  // finalize node(s); skip zero-deg
        const float inv = 1.f / (smh + 1e-16f);
        if (nd0w + cur < n)
          aTile[(wv << 2) + cur][lane] = cvt_pk_bf16(acc.x * inv, acc.y * inv);
        ++cur;
        acc.x = 0.f; acc.y = 0.f; smh = 0.f;
        rem = (cur == 1) ? d1 : (cur == 2) ? d2 : (cur == 3) ? d3 : 0;
      }
      if (cur >= 4) break;
    }
  }
  __syncthreads();

  // ---- phase 2: out-GEMM on the 16-row tile; each wave does 2 col-tiles
  const int g = lane >> 4, c = lane & 15;
#pragma unroll
  for (int t2 = 0; t2 < 2; ++t2) {
    const int nt = wv + t2 * 4;
    f32x4 o = (f32x4){0.f, 0.f, 0.f, 0.f};
#pragma unroll
    for (int ks = 0; ks < 4; ++ks) {
      uint4 au = *(const uint4*)&aTile[c][ks * 16 + g * 4];  // A row = lane&15
      short8 af = __builtin_bit_cast(short8, au);
      short8 bf = *(const short8*)(owf + ((size_t)(ks * 8 + nt) * 64 + lane) * 8);
      o = __builtin_amdgcn_mfma_f32_16x16x32_bf16(af, bf, o, 0, 0, 0);
    }
#pragma unroll
    for (int r = 0; r < 4; ++r) {
      const int row = nd0 + g * 4 + r;   // D row = (lane>>4)*4 + r
      if (row < n) {
        float v = o[r] + ob[nt * 16 + c];
        v = v > 0.f ? v : expm1f(v);
        out[(size_t)row * 128 + nt * 16 + c] = v;
      }
    }
  }
}

// ---------------------------------------------------------------- launch
extern "C" void kernel_launch(void* const* d_in, const int* in_sizes, int n_in,
                              void* d_out, int out_size, void* d_ws, size_t ws_size,
                              hipStream_t stream) {
  const float* x    = (const float*)d_in[0];
  const int*   edges = (const int*)d_in[1];   // [2,E] (src row then dst row)
  const float* W    = (const float*)d_in[2];
  const float* attn = (const float*)d_in[3];
  const float* ow   = (const float*)d_in[4];
  const float* ob   = (const float*)d_in[5];
  const int n = in_sizes[0] / 128;            // 50000 (< 65536: u32 edge pack)
  const int E = in_sizes[1] / 2;
  float* out = (float*)d_out;

  char* wp = (char*)d_ws;
  auto alloc = [&](size_t bytes) {
    char* p = wp;
    wp += (bytes + 255) & ~(size_t)255;
    return p;
  };
  unsigned short* wf  = (unsigned short*)alloc(2048 * 8 * 2);
  unsigned short* owf = (unsigned short*)alloc(2048 * 8 * 2);
  unsigned short* abf = (unsigned short*)alloc(256 * 8 * 2);
  unsigned int*   Wxb = (unsigned int*)alloc((size_t)n * 64 * 4);
  float* s_i    = (float*)alloc((size_t)n * 4 * 4);
  float* s_j    = (float*)alloc((size_t)n * 4 * 4);
  int*   gcnt   = (int*)alloc(256 * 4);
  int*   gcur   = (int*)alloc(256 * 4);
  int*   offs   = (int*)alloc((size_t)n * 4);
  int*   cnts   = (int*)alloc((size_t)n * 4);
  unsigned int* tmp = (unsigned int*)alloc((size_t)E * 4);
  int*   csr    = (int*)alloc((size_t)E * 4);

  dim3 blk(256);
  const int NB = (n + 255) / 256;                            // node buckets (196)
  const int EB = (E + 256 * BIN_VPT - 1) / (256 * BIN_VPT);  // edge blocks (196)
  const int strips = (n + 15) / 16;
  const int gemmBlocks = (strips + 3) / 4;

  k_setup<<<17, blk, 0, stream>>>(W, ow, attn, wf, owf, abf, gcnt, gcur);
  k_gemm1b<<<gemmBlocks + EB, blk, 0, stream>>>(x, wf, abf, Wxb, s_i, s_j, n,
                                                edges + E, gcnt, E, gemmBlocks);
  k_bin1<<<EB, blk, 0, stream>>>(edges, gcnt, gcur, tmp, E);
  k_bin2<<<NB, blk, 0, stream>>>(tmp, gcnt, csr, offs, cnts, n);
  k_aggm<<<(n + 15) / 16, blk, 0, stream>>>(Wxb, s_i, s_j, offs, cnts, csr,
                                            owf, ob, out, n);
}

// Round 15
// 91.701 us; speedup vs baseline: 1.8923x; 1.0175x over previous
//
#include <hip/hip_runtime.h>
#include <math.h>

// GAT layer: N=50000 nodes, E=800000 edges, D_IN=D_OUT=128, H=4, D_H=32
//
// Dispatch graph (restructured for overlap; kernel bodies = round-14):
//   memset   : zero gcnt/gcur (2 KB)
//   L1 k_su_hist : blocks 0-16 = frag pack (W, out_w, Mw = W@att_full);
//                  blocks 17+  = dst-bucket histogram (needs only edges)
//   L2 k_g1_bin1 : blocks [0,gemmBlocks) = Wx(bf16) = x @ W via MFMA with
//                  s_i/s_j as ONE extra MFMA per ks (B = Mw fragments);
//                  blocks [gemmBlocks,+EB) = bin1 counting sort -> tmp
//                  (independent of the GEMM; fills CU slack behind it)
//   L3 k_bin2   : one block per bucket: node counts + scan (offs/cnts) +
//                 placement — all scatter block-private
//   L4 k_aggm   : 4 waves/block, 4 consecutive nodes/wave; LDS-staged
//                 (csr + s_i gather + exp); consumer = full 256B row per
//                 wave instruction, 8 in flight; phase 2 = out-GEMM + ELU.
//                 (~4.7 TB/s effective random gather — measured floor over
//                 6 structural variants, rounds 7-12.)

typedef __attribute__((ext_vector_type(8))) short short8;
typedef __attribute__((ext_vector_type(4))) float f32x4;

#define BIN_VPT 16          // edges per thread; 4096 edges per 256-thread block

__device__ __forceinline__ float lrelu(float v) { return v >= 0.f ? v : 0.2f * v; }

__device__ __forceinline__ unsigned short f2bf(float f) {  // RNE f32 -> bf16
  unsigned int u = __float_as_uint(f);
  u += 0x7FFFu + ((u >> 16) & 1u);
  return (unsigned short)(u >> 16);
}
// HW packed RNE convert: dst = bf16(lo) | bf16(hi)<<16
__device__ __forceinline__ unsigned int cvt_pk_bf16(float lo, float hi) {
  unsigned int r;
  asm("v_cvt_pk_bf16_f32 %0, %1, %2" : "=v"(r) : "v"(lo), "v"(hi));
  return r;
}
__device__ __forceinline__ float bflo(unsigned int w) { return __uint_as_float(w << 16); }
__device__ __forceinline__ float bfhi(unsigned int w) { return __uint_as_float(w & 0xFFFF0000u); }

// 256-thread exclusive scan helper (value v per thread -> returns excl; ws[4] LDS)
__device__ __forceinline__ int blk_excl_scan(int v, int* ws) {
  const int t = threadIdx.x, lane = t & 63, wv = t >> 6;
  int incl = v;
#pragma unroll
  for (int m = 1; m < 64; m <<= 1) {
    int x = __shfl_up(incl, m, 64);
    if (lane >= m) incl += x;
  }
  if (lane == 63) ws[wv] = incl;
  __syncthreads();
  int woff = 0;
  for (int p = 0; p < wv; ++p) woff += ws[p];
  return woff + incl - v;
}

// ---------------------------------------------------------------- L1: setup + hist
// blocks 0..7: W fragments; 8..15: out_w fragments; 16: Mw fragments;
// blocks 17..17+EB: dst-bucket histogram (gcnt pre-zeroed by memset).
__global__ void k_su_hist(const float* __restrict__ W, const float* __restrict__ ow,
                          const float* __restrict__ attn,
                          unsigned short* __restrict__ wf, unsigned short* __restrict__ owf,
                          unsigned short* __restrict__ abf,
                          const int* __restrict__ dst, int* __restrict__ gcnt, int E) {
  __shared__ float Mw[128][16];
  __shared__ int lc[256];
  if (blockIdx.x >= 17) {  // ---- histogram part
    const int bb = blockIdx.x - 17;
    lc[threadIdx.x] = 0;
    __syncthreads();
    const int base = bb * (256 * BIN_VPT);
#pragma unroll
    for (int j = 0; j < BIN_VPT; ++j) {
      int e = base + j * 256 + threadIdx.x;
      if (e < E) atomicAdd(&lc[((unsigned int)dst[e]) >> 8], 1);
    }
    __syncthreads();
    int c = lc[threadIdx.x];
    if (c) atomicAdd(&gcnt[threadIdx.x], c);
    return;
  }
  if (blockIdx.x == 16) {
    // ---- compute Mw = W @ att_full in f32 (LDS), then pack bf16 fragments
    const int t = threadIdx.x;
    if (t < 128) {
      float v[16];
#pragma unroll
      for (int c = 0; c < 16; ++c) v[c] = 0.f;
#pragma unroll
      for (int h = 0; h < 4; ++h) {
        float si = 0.f, sj = 0.f;
        for (int dd = 0; dd < 32; ++dd) {
          const float w = W[t * 128 + h * 32 + dd];
          si += w * attn[h * 64 + dd];
          sj += w * attn[h * 64 + 32 + dd];
        }
        v[h] = si;
        v[4 + h] = sj;
      }
#pragma unroll
      for (int c = 0; c < 16; ++c) Mw[t][c] = v[c];
    }
    __syncthreads();
    const int t2 = threadIdx.x;
    const int lane = t2 & 63;
    const int ks = t2 >> 6;                // 0..3
    const int k0 = ks * 32 + (lane >> 4) * 8;
    const int col = lane & 15;
    short8 vv;
#pragma unroll
    for (int j = 0; j < 8; ++j) vv[j] = (short)f2bf(Mw[k0 + j][col]);
    *(short8*)(abf + ((size_t)(ks * 64 + lane)) * 8) = vv;
    return;
  }
  const int t = blockIdx.x * 256 + threadIdx.x;
  const int which = t >> 11;           // 0: W, 1: out_w
  const int tt = t & 2047;
  const float* M = which ? ow : W;
  unsigned short* F = which ? owf : wf;
  const int lane = tt & 63;
  const int nt = (tt >> 6) & 7;
  const int ks = tt >> 9;
  const int k0 = ks * 32 + (lane >> 4) * 8;
  const int col = nt * 16 + (lane & 15);
  short8 v;
#pragma unroll
  for (int j = 0; j < 8; ++j) v[j] = (short)f2bf(M[(k0 + j) * 128 + col]);
  *(short8*)(F + (size_t)tt * 8) = v;
}

// ---------------------------------------------------------------- L2: GEMM1 + bin1
__global__ void k_g1_bin1(const float* __restrict__ x, const unsigned short* __restrict__ wf,
                          const unsigned short* __restrict__ abf,
                          unsigned int* __restrict__ Wxb,
                          float* __restrict__ s_i, float* __restrict__ s_j, int n,
                          const int* __restrict__ edges, const int* __restrict__ gcnt,
                          int* __restrict__ gcur, unsigned int* __restrict__ tmp, int E,
                          int gemmBlocks) {
  __shared__ int ws[4];
  __shared__ int bst_s[256];
  __shared__ int lcnt[256];
  __shared__ int lbase[256];
  if (blockIdx.x >= gemmBlocks) {  // ---- bin1 part (counting sort into tmp)
    const int bb = blockIdx.x - gemmBlocks;
    const int t = threadIdx.x;
    const int excl = blk_excl_scan(gcnt[t], ws);
    bst_s[t] = excl;
    lcnt[t] = 0;
    __syncthreads();
    const int base = bb * (256 * BIN_VPT);
    unsigned int pv[BIN_VPT];
    int rk[BIN_VPT];
#pragma unroll
    for (int j = 0; j < BIN_VPT; ++j) {
      int e = base + j * 256 + t;
      if (e < E) {
        unsigned int s = (unsigned int)edges[e];
        unsigned int d = (unsigned int)edges[E + e];
        pv[j] = s | (d << 16);
        rk[j] = atomicAdd(&lcnt[d >> 8], 1);
      } else {
        pv[j] = 0u;
        rk[j] = -1;
      }
    }
    __syncthreads();
    const int c = lcnt[t];
    lbase[t] = bst_s[t] + (c ? atomicAdd(&gcur[t], c) : 0);
    __syncthreads();
#pragma unroll
    for (int j = 0; j < BIN_VPT; ++j) {
      if (rk[j] >= 0) {
        const int b = pv[j] >> 24;  // dst >> 8
        tmp[lbase[b] + rk[j]] = pv[j];
      }
    }
    return;
  }

  // ---- GEMM part: one wave = 16-row strip, acc[nt] covers cols nt*16..+15
  const int lane = threadIdx.x & 63;
  const int gw = blockIdx.x * (blockDim.x >> 6) + (threadIdx.x >> 6);
  const int r0 = gw * 16;
  if (r0 >= n) return;
  const int g = lane >> 4, c = lane & 15;

  f32x4 acc[8];
#pragma unroll
  for (int nt = 0; nt < 8; ++nt) acc[nt] = (f32x4){0.f, 0.f, 0.f, 0.f};
  f32x4 sacc = (f32x4){0.f, 0.f, 0.f, 0.f};

  const int arow = min(r0 + c, n - 1);
#pragma unroll
  for (int ks = 0; ks < 4; ++ks) {
    const float* xr = x + (size_t)arow * 128 + ks * 32 + g * 8;
    float4 v0 = *(const float4*)xr;
    float4 v1 = *(const float4*)(xr + 4);
    uint4 au;
    au.x = cvt_pk_bf16(v0.x, v0.y);
    au.y = cvt_pk_bf16(v0.z, v0.w);
    au.z = cvt_pk_bf16(v1.x, v1.y);
    au.w = cvt_pk_bf16(v1.z, v1.w);
    short8 af = __builtin_bit_cast(short8, au);
#pragma unroll
    for (int nt = 0; nt < 8; ++nt) {
      short8 bf = *(const short8*)(wf + ((size_t)(ks * 8 + nt) * 64 + lane) * 8);
      acc[nt] = __builtin_amdgcn_mfma_f32_16x16x32_bf16(af, bf, acc[nt], 0, 0, 0);
    }
    // s_i/s_j: one extra MFMA per ks (B = Mw fragments)
    short8 ab = *(const short8*)(abf + ((size_t)(ks * 64 + lane)) * 8);
    sacc = __builtin_amdgcn_mfma_f32_16x16x32_bf16(af, ab, sacc, 0, 0, 0);
  }

  const int odd = c & 1;
#pragma unroll
  for (int r = 0; r < 4; ++r) {
    const int row = r0 + g * 4 + r;
    if (row >= n) continue;
    unsigned int* dp = Wxb + (size_t)row * 64;
#pragma unroll
    for (int ntp = 0; ntp < 4; ++ntp) {
      float ve = acc[ntp][r], vo = acc[ntp + 4][r];
      float vex = __shfl_xor(ve, 1, 64);
      float vox = __shfl_xor(vo, 1, 64);
      const int nt = odd ? ntp + 4 : ntp;
      dp[nt * 8 + (c >> 1)] = cvt_pk_bf16(odd ? vox : ve, odd ? vo : vex);
    }
  }

  // s write: D(lane,r) -> row=(lane>>4)*4+r, col=lane&15; cols 0-3 = s_i
  // heads, 4-7 = s_j heads.
#pragma unroll
  for (int r = 0; r < 4; ++r) {
    const int row = r0 + g * 4 + r;
    if (row < n) {
      if (c < 4)      s_i[(size_t)row * 4 + c] = sacc[r];
      else if (c < 8) s_j[(size_t)row * 4 + (c - 4)] = sacc[r];
    }
  }
}

// ---------------------------------------------------------------- L3: bin2
__global__ void k_bin2(const unsigned int* __restrict__ tmp, const int* __restrict__ gcnt,
                       int* __restrict__ csr, int* __restrict__ offs,
                       int* __restrict__ cnts, int n) {
  __shared__ int ws[4];
  __shared__ int bst_s[256];
  __shared__ int nc[256];
  const int b = blockIdx.x;
  const int t = threadIdx.x;
  bst_s[t] = blk_excl_scan(gcnt[t], ws);
  nc[t] = 0;
  __syncthreads();
  const int base = bst_s[b], cnt = gcnt[b];
  for (int i = t; i < cnt; i += 256)
    atomicAdd(&nc[(tmp[base + i] >> 16) & 255], 1);
  __syncthreads();
  const int node = b * 256 + t;
  const int c = nc[t];
  if (node < n) cnts[node] = c;
  __syncthreads();           // blk_excl_scan reuses ws; ensure count phase done
  const int excl = blk_excl_scan(c, ws);
  if (node < n) offs[node] = base + excl;
  __syncthreads();           // everyone done reading nc from count phase
  nc[t] = excl;              // becomes local cursor
  __syncthreads();
  for (int i = t; i < cnt; i += 256) {
    unsigned int v = tmp[base + i];
    int pos = atomicAdd(&nc[(v >> 16) & 255], 1);
    csr[base + pos] = (int)(v & 0xFFFFu);
  }
}

// ---------------------------------------------------------------- L4: agg + GEMM2
// 4 waves/block (256 thr), 16 nodes/block, 4 consecutive nodes per wave.
#define AGG_EDGE(e)                                                     \
  {                                                                     \
    int s_ = lsrc[wv][e];                                               \
    float p_ = lp[wv][e][h];                                            \
    unsigned int w_ = Wxb[(unsigned)(s_ << 6) | (unsigned)lane];        \
    acc.x += p_ * bflo(w_);                                             \
    acc.y += p_ * bfhi(w_);                                             \
    smh += p_;                                                          \
  }

__global__ void k_aggm(const unsigned int* __restrict__ Wxb, const float* __restrict__ s_i,
                       const float* __restrict__ s_j, const int* __restrict__ offs,
                       const int* __restrict__ cnts, const int* __restrict__ csr_src,
                       const unsigned short* __restrict__ owf, const float* __restrict__ ob,
                       float* __restrict__ out, int n) {
  __shared__ unsigned int aTile[16][65];
  __shared__ int   lsrc[4][64];
  __shared__ float lp[4][64][4];
  const int lane = threadIdx.x & 63;
  const int wv = threadIdx.x >> 6;
  const int nd0 = blockIdx.x * 16;
  const int nd0w = nd0 + wv * 4;       // first of this wave's 4 nodes
  const int h = lane >> 4;

  // per-node degrees in lanes 0..3; boundaries b0<b1<b2 within the wave span
  int degv = 0;
  if (lane < 4 && nd0w + lane < n) degv = cnts[nd0w + lane];
  const int wbase = (nd0w < n) ? offs[nd0w] : 0;
  const int d0 = __shfl(degv, 0, 64), d1 = __shfl(degv, 1, 64);
  const int d2 = __shfl(degv, 2, 64), d3 = __shfl(degv, 3, 64);
  const int b0 = d0, b1 = d0 + d1, b2 = b1 + d2;
  const int tot = b2 + d3;

  int cur = 0;
  int rem = d0;
  float2 acc = make_float2(0.f, 0.f);
  float smh = 0.f;

  // leading zero-degree nodes
  while (cur < 4 && rem == 0) {
    if (nd0w + cur < n) aTile[(wv << 2) + cur][lane] = 0u;  // agg row = 0
    ++cur;
    rem = (cur == 1) ? d1 : (cur == 2) ? d2 : (cur == 3) ? d3 : 0;
  }

  for (int c0 = 0; c0 < tot; c0 += 64) {
    const int m = min(64, tot - c0);
    if (lane < m) {
      const int pos = c0 + lane;
      const int src = csr_src[wbase + pos];
      const int nl = (pos >= b0) + (pos >= b1) + (pos >= b2);
      const float4 sj = *(const float4*)(s_j + (size_t)(nd0w + nl) * 4);
      const float4 si = *(const float4*)(s_i + (size_t)src * 4);
      float4 p;
      p.x = __expf(lrelu(si.x + sj.x));
      p.y = __expf(lrelu(si.y + sj.y));
      p.z = __expf(lrelu(si.z + sj.z));
      p.w = __expf(lrelu(si.w + sj.w));
      lsrc[wv][lane] = src;
      *(float4*)&lp[wv][lane][0] = p;
    }
    asm volatile("s_waitcnt lgkmcnt(0)" ::: "memory");  // same-wave LDS RAW
    int k = 0;
    while (k < m) {
      const int take = min(m - k, rem);
      int e = k;
      const int end = k + take;
      for (; e + 8 <= end; e += 8) {  // 8 independent 256B row loads in flight
        AGG_EDGE(e + 0) AGG_EDGE(e + 1) AGG_EDGE(e + 2) AGG_EDGE(e + 3)
        AGG_EDGE(e + 4) AGG_EDGE(e + 5) AGG_EDGE(e + 6) AGG_EDGE(e + 7)
      }
      for (; e + 4 <= end; e += 4) {
        AGG_EDGE(e + 0) AGG_EDGE(e + 1) AGG_EDGE(e + 2) AGG_EDGE(e + 3)
      }
      for (; e < end; ++e) AGG_EDGE(e)
      k += take;
      rem -= take;
      while (rem == 0 && cur < 4) {  // finalize node(s); skip zero-deg
        const float inv = 1.f / (smh + 1e-16f);
        if (nd0w + cur < n)
          aTile[(wv << 2) + cur][lane] = cvt_pk_bf16(acc.x * inv, acc.y * inv);
        ++cur;
        acc.x = 0.f; acc.y = 0.f; smh = 0.f;
        rem = (cur == 1) ? d1 : (cur == 2) ? d2 : (cur == 3) ? d3 : 0;
      }
      if (cur >= 4) break;
    }
  }
  __syncthreads();

  // ---- phase 2: out-GEMM on the 16-row tile; each wave does 2 col-tiles
  const int g = lane >> 4, c = lane & 15;
#pragma unroll
  for (int t2 = 0; t2 < 2; ++t2) {
    const int nt = wv + t2 * 4;
    f32x4 o = (f32x4){0.f, 0.f, 0.f, 0.f};
#pragma unroll
    for (int ks = 0; ks < 4; ++ks) {
      uint4 au = *(const uint4*)&aTile[c][ks * 16 + g * 4];  // A row = lane&15
      short8 af = __builtin_bit_cast(short8, au);
      short8 bf = *(const short8*)(owf + ((size_t)(ks * 8 + nt) * 64 + lane) * 8);
      o = __builtin_amdgcn_mfma_f32_16x16x32_bf16(af, bf, o, 0, 0, 0);
    }
#pragma unroll
    for (int r = 0; r < 4; ++r) {
      const int row = nd0 + g * 4 + r;   // D row = (lane>>4)*4 + r
      if (row < n) {
        float v = o[r] + ob[nt * 16 + c];
        v = v > 0.f ? v : expm1f(v);
        out[(size_t)row * 128 + nt * 16 + c] = v;
      }
    }
  }
}

// ---------------------------------------------------------------- launch
extern "C" void kernel_launch(void* const* d_in, const int* in_sizes, int n_in,
                              void* d_out, int out_size, void* d_ws, size_t ws_size,
                              hipStream_t stream) {
  const float* x    = (const float*)d_in[0];
  const int*   edges = (const int*)d_in[1];   // [2,E] (src row then dst row)
  const float* W    = (const float*)d_in[2];
  const float* attn = (const float*)d_in[3];
  const float* ow   = (const float*)d_in[4];
  const float* ob   = (const float*)d_in[5];
  const int n = in_sizes[0] / 128;            // 50000 (< 65536: u32 edge pack)
  const int E = in_sizes[1] / 2;
  float* out = (float*)d_out;

  char* wp = (char*)d_ws;
  auto alloc = [&](size_t bytes) {
    char* p = wp;
    wp += (bytes + 255) & ~(size_t)255;
    return p;
  };
  unsigned short* wf  = (unsigned short*)alloc(2048 * 8 * 2);
  unsigned short* owf = (unsigned short*)alloc(2048 * 8 * 2);
  unsigned short* abf = (unsigned short*)alloc(256 * 8 * 2);
  unsigned int*   Wxb = (unsigned int*)alloc((size_t)n * 64 * 4);
  float* s_i    = (float*)alloc((size_t)n * 4 * 4);
  float* s_j    = (float*)alloc((size_t)n * 4 * 4);
  int*   gcnt   = (int*)alloc(256 * 4);
  int*   gcur   = (int*)alloc(256 * 4);
  int*   offs   = (int*)alloc((size_t)n * 4);
  int*   cnts   = (int*)alloc((size_t)n * 4);
  unsigned int* tmp = (unsigned int*)alloc((size_t)E * 4);
  int*   csr    = (int*)alloc((size_t)E * 4);

  dim3 blk(256);
  const int NB = (n + 255) / 256;                            // node buckets (196)
  const int EB = (E + 256 * BIN_VPT - 1) / (256 * BIN_VPT);  // edge blocks (196)
  const int strips = (n + 15) / 16;
  const int gemmBlocks = (strips + 3) / 4;

  // gcnt/gcur are contiguous (each 1024 B, 256-aligned) -> one 2 KB memset
  hipMemsetAsync(gcnt, 0, 2048, stream);
  k_su_hist<<<17 + EB, blk, 0, stream>>>(W, ow, attn, wf, owf, abf,
                                         edges + E, gcnt, E);
  k_g1_bin1<<<gemmBlocks + EB, blk, 0, stream>>>(x, wf, abf, Wxb, s_i, s_j, n,
                                                 edges, gcnt, gcur, tmp, E,
                                                 gemmBlocks);
  k_bin2<<<NB, blk, 0, stream>>>(tmp, gcnt, csr, offs, cnts, n);
  k_aggm<<<(n + 15) / 16, blk, 0, stream>>>(Wxb, s_i, s_j, offs, cnts, csr,
                                            owf, ob, out, n);
}